// Round 10
// baseline (186.252 us; speedup 1.0000x reference)
//
#include <hip/hip_runtime.h>
#include <math.h>

#define NN 2048
#define FD 512
#define DXF 256
#define JC 8
#define CHKJ (NN/JC)      // 256
#define ITI 32
#define JTW 64
#define NIT (CHKJ/JTW)    // 4
#define KC (NN/4)         // 512 (xm split-K chunk)

typedef unsigned short u16;
typedef unsigned int u32;
typedef __attribute__((ext_vector_type(8))) short s16x8;
typedef __attribute__((ext_vector_type(4))) float f32x4;

__device__ __forceinline__ f32x4 MFMA16(s16x8 a, s16x8 b, f32x4 c) {
  return __builtin_amdgcn_mfma_f32_16x16x32_bf16(a, b, c, 0, 0, 0);
}
__device__ __forceinline__ float blo(u32 u) { return __uint_as_float(u << 16); }
__device__ __forceinline__ float bhi(u32 u) { return __uint_as_float(u & 0xffff0000u); }
__device__ __forceinline__ float b2f(u16 v) { return __uint_as_float((u32)v << 16); }
__device__ __forceinline__ u16 bf1(float f) {
  u32 u = __float_as_uint(f);
  u += 0x7fffu + ((u >> 16) & 1u);
  return (u16)(u >> 16);
}
__device__ __forceinline__ u32 pkbf(float a, float b) {
  u32 ua = __float_as_uint(a), ub = __float_as_uint(b);
  ua += 0x7fffu + ((ua >> 16) & 1u);
  ub += 0x7fffu + ((ub >> 16) & 1u);
  return (ua >> 16) | (ub & 0xffff0000u);
}

// ---------- merged preprocessing: ln rows, xn rows, weight converts ----------
__global__ void preproc_k(
    const float* __restrict__ h, const float* __restrict__ ln_g,
    const float* __restrict__ ln_b, u16* __restrict__ hnB,
    const float* __restrict__ x, u16* __restrict__ xnB,
    const float* __restrict__ Wk, const float* __restrict__ Wq,
    const float* __restrict__ Wv, u16* __restrict__ wkB, u16* __restrict__ wqB,
    u16* __restrict__ wvB, const float* __restrict__ Wfc, u16* __restrict__ wfcB) {
  int bid = blockIdx.x, t = threadIdx.x;
  __shared__ float red[4][2];
  if (bid < NN) {
    int r = bid;
    float2 v = ((const float2*)(h + (size_t)r * FD))[t];
    float2 w = make_float2(v.x + v.y, v.x * v.x + v.y * v.y);
#pragma unroll
    for (int o = 32; o > 0; o >>= 1) { w.x += __shfl_xor(w.x, o); w.y += __shfl_xor(w.y, o); }
    if ((t & 63) == 0) { red[t >> 6][0] = w.x; red[t >> 6][1] = w.y; }
    __syncthreads();
    float S  = (red[0][0] + red[1][0]) + (red[2][0] + red[3][0]);
    float SQ = (red[0][1] + red[1][1]) + (red[2][1] + red[3][1]);
    float mean = S * (1.f / FD);
    float var  = SQ * (1.f / FD) - mean * mean;
    float rs = rsqrtf(var + 1e-5f);
    float2 gg = ((const float2*)ln_g)[t], bb = ((const float2*)ln_b)[t];
    float ox = (v.x - mean) * rs * gg.x + bb.x;
    float oy = (v.y - mean) * rs * gg.y + bb.y;
    *(u32*)(hnB + (size_t)r * FD + 2 * t) = pkbf(ox, oy);
  } else if (bid < 2 * NN) {
    int r = bid - NN;
    float v = x[(size_t)r * DXF + t];
    float s = fabsf(v);
#pragma unroll
    for (int o = 32; o > 0; o >>= 1) s += __shfl_xor(s, o);
    if ((t & 63) == 0) red[t >> 6][0] = s;
    __syncthreads();
    float S = (red[0][0] + red[1][0]) + (red[2][0] + red[3][0]);
    float inv = 1.f / fmaxf(S, 1e-12f);
    xnB[(size_t)r * DXF + t] = bf1(v * inv);
  } else if (bid < 2 * NN + 1536) {
    int idx = bid - 2 * NN;
    int z = idx >> 9;
    int i = ((idx & 511) << 8) + t;
    const float* W = (z == 0) ? Wk : (z == 1) ? Wq : Wv;
    u16* O = (z == 0) ? wkB : (z == 1) ? wqB : wvB;
    float2 v = ((const float2*)W)[i];
    ((u32*)O)[i] = pkbf(v.x, v.y);
  } else {
    int i = (bid - (2 * NN + 1536)) * 256 + t;
    if (i < 512 * 272) {
      int r = i / 272, c2 = (i - r * 272) * 2;
      float a = (c2 < 516) ? Wfc[r * 516 + c2] : 0.f;
      float b = (c2 + 1 < 516) ? Wfc[r * 516 + c2 + 1] : 0.f;
      ((u32*)wfcB)[i] = pkbf(a, b);
    }
  }
}

// ---------- transpose xnB [NN][256] -> xnTg [256][NN] ----------
__global__ void xnt_k(const u16* __restrict__ xnB, u16* __restrict__ xnTg) {
  __shared__ u16 tile[16][264];
  int t = threadIdx.x;
  int r0 = blockIdx.x * 16;
#pragma unroll
  for (int s = 0; s < 2; ++s) {
    int c = s * 256 + t;
    int db = c & 31, row = c >> 5;
    *(uint4*)&tile[row][db * 8] = *(const uint4*)(xnB + (size_t)(r0 + row) * DXF + db * 8);
  }
  __syncthreads();
#pragma unroll
  for (int s = 0; s < 2; ++s) {
    int c = s * 256 + t;
    int jb = c & 1, d = c >> 1;
    u32 p[4];
#pragma unroll
    for (int e2 = 0; e2 < 4; ++e2) {
      u16 a = tile[jb * 8 + e2 * 2][d], b = tile[jb * 8 + e2 * 2 + 1][d];
      p[e2] = (u32)a | ((u32)b << 16);
    }
    *(uint4*)(xnTg + (size_t)d * NN + r0 + jb * 8) = make_uint4(p[0], p[1], p[2], p[3]);
  }
}

// ---------- batched projection GEMM: z=0 kP planar, z=1 qP planar, z=2 vPT ----------
__global__ __launch_bounds__(256) void proj3_k(
    const u16* __restrict__ A,
    const u16* __restrict__ W0, const u16* __restrict__ W1, const u16* __restrict__ W2,
    const float* __restrict__ b0, const float* __restrict__ b1, const float* __restrict__ b2,
    u16* __restrict__ kP, u16* __restrict__ qP, u16* __restrict__ vPT) {
  int z = blockIdx.z;
  const u16* B = (z == 0) ? W0 : (z == 1) ? W1 : W2;
  const float* bias = (z == 0) ? b0 : (z == 1) ? b1 : b2;
  int t = threadIdx.x, w = t >> 6, lane = t & 63, g = lane >> 4, li = lane & 15;
  int m0 = blockIdx.x * 64 + (w & 1) * 32;
  int n0 = blockIdx.y * 64 + (w >> 1) * 32;
  f32x4 acc[2][2] = {};
  for (int k0 = 0; k0 < FD; k0 += 32) {
    s16x8 a0 = *(const s16x8*)(A + (size_t)(m0 + li) * FD + k0 + g * 8);
    s16x8 a1 = *(const s16x8*)(A + (size_t)(m0 + 16 + li) * FD + k0 + g * 8);
    s16x8 bA = *(const s16x8*)(B + (size_t)(n0 + li) * FD + k0 + g * 8);
    s16x8 bB = *(const s16x8*)(B + (size_t)(n0 + 16 + li) * FD + k0 + g * 8);
    acc[0][0] = MFMA16(a0, bA, acc[0][0]);
    acc[0][1] = MFMA16(a0, bB, acc[0][1]);
    acc[1][0] = MFMA16(a1, bA, acc[1][0]);
    acc[1][1] = MFMA16(a1, bB, acc[1][1]);
  }
#pragma unroll
  for (int ms = 0; ms < 2; ++ms)
#pragma unroll
    for (int ns = 0; ns < 2; ++ns) {
      int ncol = n0 + ns * 16 + li;
      float bv = bias[ncol];
      if (z < 2) {
        u16* out = z ? qP : kP;
#pragma unroll
        for (int r = 0; r < 4; ++r) {
          int i = m0 + ms * 16 + g * 4 + r;
          out[((size_t)(ncol & 7) * NN + i) * 64 + (ncol >> 3)] = bf1(acc[ms][ns][r] + bv);
        }
      } else {
        u16 e[4];
#pragma unroll
        for (int r = 0; r < 4; ++r) e[r] = bf1(acc[ms][ns][r] + bv);
        u32 p0 = (u32)e[0] | ((u32)e[1] << 16);
        u32 p1 = (u32)e[2] | ((u32)e[3] << 16);
        int ib = m0 + ms * 16 + g * 4;
        *(uint2*)(vPT + ((size_t)((ncol & 7) * 64 + (ncol >> 3))) * NN + ib) =
            make_uint2(p0, p1);
      }
    }
}

// ---------- fc GEMM (32x32 tiles): elu + residual ----------
__global__ __launch_bounds__(256) void fc_gemm_k(
    const u16* __restrict__ A, const u16* __restrict__ B,
    const float* __restrict__ bias, const float* __restrict__ res,
    float* __restrict__ C) {
  int t = threadIdx.x, w = t >> 6, lane = t & 63, g = lane >> 4, li = lane & 15;
  int m0 = blockIdx.x * 32 + (w & 1) * 16;
  int n0 = blockIdx.y * 32 + (w >> 1) * 16;
  f32x4 acc = {};
  for (int k0 = 0; k0 < 544; k0 += 32) {
    s16x8 a0 = *(const s16x8*)(A + (size_t)(m0 + li) * 544 + k0 + g * 8);
    s16x8 b0 = *(const s16x8*)(B + (size_t)(n0 + li) * 544 + k0 + g * 8);
    acc = MFMA16(a0, b0, acc);
  }
  int ncol = n0 + li;
  float bv = bias[ncol];
#pragma unroll
  for (int r = 0; r < 4; ++r) {
    int i = m0 + g * 4 + r;
    float cv = acc[r] + bv;
    cv = (cv > 0.f) ? cv : (expf(cv) - 1.f);
    cv += res[(size_t)i * FD + ncol];
    C[(size_t)i * FD + ncol] = cv;
  }
}

// ---------- xm GEMM split-K + partial row stats of axg ----------
__global__ __launch_bounds__(256) void xm_split_k(
    const u16* __restrict__ axg, const u16* __restrict__ xnTg,
    float* __restrict__ xmp, float* __restrict__ stq) {
  int t = threadIdx.x, w = t >> 6, lane = t & 63, g = lane >> 4, li = lane & 15;
  int m0 = blockIdx.x * 64 + (w & 1) * 32;
  int n0 = blockIdx.y * 64 + (w >> 1) * 32;
  int z = blockIdx.z;
  const int kb = z * KC;
  f32x4 acc[2][2] = {};
  float sab[2] = {0.f, 0.f}, ssu[2] = {0.f, 0.f}, ssq[2] = {0.f, 0.f};
  float smx[2] = {-1e30f, -1e30f};
  const bool do_stats = (blockIdx.y == 0) && ((w >> 1) == 0);
  for (int k0 = 0; k0 < KC; k0 += 32) {
    s16x8 a0 = *(const s16x8*)(axg + (size_t)(m0 + li) * NN + kb + k0 + g * 8);
    s16x8 a1 = *(const s16x8*)(axg + (size_t)(m0 + 16 + li) * NN + kb + k0 + g * 8);
    s16x8 bA = *(const s16x8*)(xnTg + (size_t)(n0 + li) * NN + kb + k0 + g * 8);
    s16x8 bB = *(const s16x8*)(xnTg + (size_t)(n0 + 16 + li) * NN + kb + k0 + g * 8);
    acc[0][0] = MFMA16(a0, bA, acc[0][0]);
    acc[0][1] = MFMA16(a0, bB, acc[0][1]);
    acc[1][0] = MFMA16(a1, bA, acc[1][0]);
    acc[1][1] = MFMA16(a1, bB, acc[1][1]);
    if (do_stats) {
#pragma unroll
      for (int ms = 0; ms < 2; ++ms) {
        u32 pu[4];
        *(s16x8*)pu = ms ? a1 : a0;
#pragma unroll
        for (int q2 = 0; q2 < 4; ++q2) {
          float x0 = blo(pu[q2]), x1 = bhi(pu[q2]);
          sab[ms] += fabsf(x0) + fabsf(x1);
          ssu[ms] += x0 + x1;
          ssq[ms] += x0 * x0 + x1 * x1;
          smx[ms] = fmaxf(smx[ms], fmaxf(x0, x1));
        }
      }
    }
  }
  if (do_stats) {
#pragma unroll
    for (int off = 16; off < 64; off <<= 1) {
#pragma unroll
      for (int ms = 0; ms < 2; ++ms) {
        sab[ms] += __shfl_xor(sab[ms], off);
        ssu[ms] += __shfl_xor(ssu[ms], off);
        ssq[ms] += __shfl_xor(ssq[ms], off);
        smx[ms] = fmaxf(smx[ms], __shfl_xor(smx[ms], off));
      }
    }
    if (g == 0) {
#pragma unroll
      for (int ms = 0; ms < 2; ++ms) {
        size_t base = ((size_t)z * NN + m0 + ms * 16 + li) * 4;
        stq[base + 0] = sab[ms]; stq[base + 1] = ssu[ms];
        stq[base + 2] = ssq[ms]; stq[base + 3] = smx[ms];
      }
    }
  }
#pragma unroll
  for (int ms = 0; ms < 2; ++ms)
#pragma unroll
    for (int ns = 0; ns < 2; ++ns) {
      int ncol = n0 + ns * 16 + li;
#pragma unroll
      for (int r = 0; r < 4; ++r) {
        int i = m0 + ms * 16 + g * 4 + r;
        xmp[(size_t)z * NN * DXF + (size_t)i * DXF + ncol] = acc[ms][ns][r];
      }
    }
}

// ---------- fused pairwise kernel: 1 barrier/iter, double-buffered P ----------
// grid (64, 8); 512 threads = 8 waves (si = w&1, jw = w>>1). i-tile 32, j-iter 64.
// All operands from global (k/xn i-rows are 4KB -> L1-resident).
// LDS = P double buffer only: 2 x [8hd][32i][128B swz] = 64 KB -> 2 blocks/CU.
// Region layout: [PV(it-1) || scores(it) || softmax(it)] -> barrier.
__global__ __launch_bounds__(512, 2) void fused_mfma_k(
    const u16* __restrict__ kP, const u16* __restrict__ qP,
    const u16* __restrict__ vPT, const u16* __restrict__ xnB,
    const float* __restrict__ Wm1, const float* __restrict__ bm1,
    const float* __restrict__ Wm2, const float* __restrict__ bm2,
    u16* __restrict__ hmPart, u16* __restrict__ axg, float* __restrict__ stPd) {
  __shared__ __align__(16) unsigned char L[65536];
  const int t = threadIdx.x, w = t >> 6, lane = t & 63;
  const int g = lane >> 4, li = lane & 15;
  const int i0 = blockIdx.x * ITI, chunk = blockIdx.y;
  const int si = w & 1;
  const int jw = w >> 1;
  const int jL = jw * 16 + li;
  const int iRow = si * 16 + li;
  const int prow = si * 16 + li;

  float W1[8][9], B1v[8];
  float C0, Cax, Cb[8];
  {
    float w2v[8];
#pragma unroll
    for (int o = 0; o < 8; ++o) {
      B1v[o] = bm1[o];
      w2v[o] = Wm2[o];
#pragma unroll
      for (int b3 = 0; b3 < 9; ++b3) W1[o][b3] = Wm1[o * 9 + b3];
    }
    C0 = bm2[0]; Cax = 1.f;
#pragma unroll
    for (int b = 0; b < 8; ++b) Cb[b] = 0.f;
#pragma unroll
    for (int o = 0; o < 8; ++o) {
      C0 += w2v[o] * B1v[o];
      Cax += w2v[o] * W1[o][0];
#pragma unroll
      for (int b = 0; b < 8; ++b) Cb[b] += w2v[o] * W1[o][1 + b];
    }
  }

  f32x4 hmA[2][4];
#pragma unroll
  for (int a = 0; a < 2; ++a)
#pragma unroll
    for (int c = 0; c < 4; ++c) hmA[a][c] = (f32x4)(0.f);

  int j0prev = 0;
  for (int it = 0; it < NIT; ++it) {
    const int j0 = chunk * CHKJ + it * JTW;
    // ---- PV for iteration it-1 (reads P[(it-1)&1]) ----
    if (it > 0) {
      const unsigned char* Pb = L + (((it - 1) & 1) << 15);
#pragma unroll
      for (int hh = 0; hh < 2; ++hh) {
        const int hd = jw * 2 + hh;
#pragma unroll
        for (int kb = 0; kb < 2; ++kb) {
          s16x8 pa = *(const s16x8*)(Pb + hd * 4096 + prow * 128 +
                                     (((kb * 4 + g) ^ (prow & 7)) << 4));
#pragma unroll
          for (int zt = 0; zt < 4; ++zt) {
            s16x8 vf = *(const s16x8*)(vPT + ((size_t)hd * 64 + zt * 16 + li) * NN +
                                       j0prev + kb * 32 + g * 8);
            hmA[hh][zt] = MFMA16(pa, vf, hmA[hh][zt]);
          }
        }
      }
    }
    // ---- scores (A/B fragments direct from global) ----
    f32x4 accS[9];
#pragma unroll
    for (int a = 0; a < 9; ++a) accS[a] = (f32x4)(0.f);
#pragma unroll
    for (int b = 0; b < 8; ++b)
#pragma unroll
      for (int ks = 0; ks < 2; ++ks) {
        s16x8 af = *(const s16x8*)(kP + ((size_t)b * NN + i0 + iRow) * 64 + ks * 32 + g * 8);
        s16x8 bf = *(const s16x8*)(qP + ((size_t)b * NN + j0 + jL) * 64 + ks * 32 + g * 8);
        accS[b] = MFMA16(af, bf, accS[b]);
      }
#pragma unroll
    for (int ks = 0; ks < 8; ++ks) {
      s16x8 af = *(const s16x8*)(xnB + (size_t)(i0 + iRow) * DXF + ks * 32 + g * 8);
      s16x8 bf = *(const s16x8*)(xnB + (size_t)(j0 + jL) * DXF + ks * 32 + g * 8);
      accS[8] = MFMA16(af, bf, accS[8]);
    }
    // ---- mixing + softmax + axn; write P[it&1] ----
    unsigned char* Pw = L + ((it & 1) << 15);
#pragma unroll
    for (int r = 0; r < 4; ++r) {
      float sb[8];
#pragma unroll
      for (int b = 0; b < 8; ++b) sb[b] = accS[b][r];
      float ax = accS[8][r];
      // axn via precomputed linear form (independent of m chain)
      float axn = C0 + Cax * ax;
#pragma unroll
      for (int b = 0; b < 8; ++b) axn += Cb[b] * sb[b];
      float m[8];
#pragma unroll
      for (int o = 0; o < 8; ++o) {
        float a = B1v[o] + W1[o][0] * ax;
#pragma unroll
        for (int b = 0; b < 8; ++b) a += W1[o][1 + b] * sb[b];
        m[o] = a;
      }
      const int iL2 = si * 16 + g * 4 + r;
      const int iG = i0 + iL2, jG = j0 + jL;
      axg[(size_t)iG * NN + jG] = bf1(axn);
      if (iG == jG) stPd[iG] = axn;
      float mx = m[0];
#pragma unroll
      for (int o = 1; o < 8; ++o) mx = fmaxf(mx, m[o]);
      float es[8], esum = 0.f;
#pragma unroll
      for (int o = 0; o < 8; ++o) { es[o] = __expf(m[o] - mx); esum += es[o]; }
      float inv = 1.f / esum;
      const int base = iL2 * 128 + (((jL >> 3) ^ (iL2 & 7)) << 4) + (jL & 7) * 2;
#pragma unroll
      for (int b = 0; b < 8; ++b)
        *(u16*)(Pw + b * 4096 + base) = bf1(es[b] * inv);
    }
    __syncthreads();  // P[it&1] visible; prev buffer readers done
    j0prev = j0;
  }
  // ---- final PV (iteration NIT-1, P[(NIT-1)&1]) ----
  {
    const unsigned char* Pb = L + (((NIT - 1) & 1) << 15);
#pragma unroll
    for (int hh = 0; hh < 2; ++hh) {
      const int hd = jw * 2 + hh;
#pragma unroll
      for (int kb = 0; kb < 2; ++kb) {
        s16x8 pa = *(const s16x8*)(Pb + hd * 4096 + prow * 128 +
                                   (((kb * 4 + g) ^ (prow & 7)) << 4));
#pragma unroll
        for (int zt = 0; zt < 4; ++zt) {
          s16x8 vf = *(const s16x8*)(vPT + ((size_t)hd * 64 + zt * 16 + li) * NN +
                                     j0prev + kb * 32 + g * 8);
          hmA[hh][zt] = MFMA16(pa, vf, hmA[hh][zt]);
        }
      }
    }
  }
  // ---- write hm partials (bf16) ----
#pragma unroll
  for (int hh = 0; hh < 2; ++hh) {
    const int hd = jw * 2 + hh;
#pragma unroll
    for (int zt = 0; zt < 4; ++zt)
#pragma unroll
      for (int r = 0; r < 4; ++r) {
        int i = i0 + si * 16 + g * 4 + r;
        int z = zt * 16 + li;
        hmPart[((size_t)(chunk * 8 + hd) * NN + i) * 64 + z] = bf1(hmA[hh][zt][r]);
      }
  }
}

// ---------- epilogue ----------
__global__ void epilogue1_k(
    const float* __restrict__ h, const float* __restrict__ x,
    const u16* __restrict__ hmp, const float* __restrict__ xmp,
    const float* __restrict__ stq, const float* __restrict__ stPd,
    const float* __restrict__ lnf_g, const float* __restrict__ lnf_b,
    float* __restrict__ hmf, u16* __restrict__ hfeB, float* __restrict__ out_xm) {
  int r = blockIdx.x, t = threadIdx.x;
  int c0 = 2 * t, c1 = c0 + 1;
  float2 acc = ((const float2*)(h + (size_t)r * FD))[t];
#pragma unroll
  for (int ch = 0; ch < JC; ++ch) {
    acc.x += b2f(hmp[((size_t)(ch * 8 + (c0 & 7)) * NN + r) * 64 + (c0 >> 3)]);
    acc.y += b2f(hmp[((size_t)(ch * 8 + (c1 & 7)) * NN + r) * 64 + (c1 >> 3)]);
  }
  ((float2*)(hmf + (size_t)r * FD))[t] = acc;
  float2 w = make_float2(acc.x + acc.y, acc.x * acc.x + acc.y * acc.y);
#pragma unroll
  for (int o = 32; o > 0; o >>= 1) { w.x += __shfl_xor(w.x, o); w.y += __shfl_xor(w.y, o); }
  __shared__ float red[4][2];
  __shared__ float s_inv;
  if ((t & 63) == 0) { red[t >> 6][0] = w.x; red[t >> 6][1] = w.y; }
  __syncthreads();
  float S  = (red[0][0] + red[1][0]) + (red[2][0] + red[3][0]);
  float SQ = (red[0][1] + red[1][1]) + (red[2][1] + red[3][1]);
  float mean = S * (1.f / FD);
  float var  = SQ * (1.f / FD) - mean * mean;
  float rs = rsqrtf(var + 1e-5f);
  float2 g2 = ((const float2*)lnf_g)[t], b2 = ((const float2*)lnf_b)[t];
  float ox = (acc.x - mean) * rs * g2.x + b2.x;
  float oy = (acc.y - mean) * rs * g2.y + b2.y;
  *(u32*)(hfeB + (size_t)r * 544 + c0) = pkbf(ox, oy);
  if (t == 0) {
    float sab = 0.f, ssu = 0.f, ssq = 0.f, smx = -1e30f;
#pragma unroll
    for (int c = 0; c < 4; ++c) {
      size_t b = ((size_t)c * NN + r) * 4;
      sab += stq[b + 0]; ssu += stq[b + 1]; ssq += stq[b + 2];
      smx = fmaxf(smx, stq[b + 3]);
    }
    float diag = stPd[r];
    float L1 = fmaxf(sab, 1e-12f);
    float inv = 1.f / L1;
    float stdv = sqrtf(fmaxf((ssq - ssu * ssu * (1.f / 2048.f)) * (1.f / 2047.f), 0.f)) * inv;
    u16* he = hfeB + (size_t)r * 544;
    he[512] = bf1(diag * inv); he[513] = bf1(ssu * inv);
    he[514] = bf1(stdv);       he[515] = bf1(smx * inv);
    s_inv = inv;
  }
  if (t < 14) *(u32*)(hfeB + (size_t)r * 544 + 516 + 2 * t) = 0;
  __syncthreads();
  float inv = s_inv;
  float xv = xmp[(size_t)r * DXF + t] + xmp[(size_t)NN * DXF + (size_t)r * DXF + t] +
             xmp[2 * (size_t)NN * DXF + (size_t)r * DXF + t] +
             xmp[3 * (size_t)NN * DXF + (size_t)r * DXF + t];
  out_xm[(size_t)r * DXF + t] = xv * inv + x[(size_t)r * DXF + t];
}

extern "C" void kernel_launch(void* const* d_in, const int* in_sizes, int n_in,
                              void* d_out, int out_size, void* d_ws, size_t ws_size,
                              hipStream_t stream) {
  (void)in_sizes; (void)n_in; (void)out_size; (void)ws_size;
  const float* h    = (const float*)d_in[0];
  const float* x    = (const float*)d_in[1];
  const float* ln_g = (const float*)d_in[2];
  const float* ln_b = (const float*)d_in[3];
  const float* Wk   = (const float*)d_in[4];
  const float* bk   = (const float*)d_in[5];
  const float* Wq   = (const float*)d_in[6];
  const float* bq   = (const float*)d_in[7];
  const float* Wv   = (const float*)d_in[8];
  const float* bv   = (const float*)d_in[9];
  const float* Wm1  = (const float*)d_in[10];
  const float* bm1  = (const float*)d_in[11];
  const float* Wm2  = (const float*)d_in[12];
  const float* bm2  = (const float*)d_in[13];
  const float* lnf_g = (const float*)d_in[14];
  const float* lnf_b = (const float*)d_in[15];
  const float* Wfc  = (const float*)d_in[16];
  const float* bfc  = (const float*)d_in[17];

  char* wsb = (char*)d_ws;
  size_t off = 0;
  auto alloc = [&](size_t bytes) { char* p = wsb + off; off += (bytes + 255) & ~(size_t)255; return p; };
  u16*   hnB  = (u16*)alloc((size_t)NN * FD * 2);
  u16*   wkB  = (u16*)alloc((size_t)FD * FD * 2);
  u16*   wqB  = (u16*)alloc((size_t)FD * FD * 2);
  u16*   wvB  = (u16*)alloc((size_t)FD * FD * 2);
  u16*   wfcB = (u16*)alloc((size_t)512 * 544 * 2);
  u16*   kP   = (u16*)alloc((size_t)8 * NN * 64 * 2);
  u16*   qP   = (u16*)alloc((size_t)8 * NN * 64 * 2);
  u16*   vPT  = (u16*)alloc((size_t)8 * 64 * NN * 2);
  u16*   xnB  = (u16*)alloc((size_t)NN * DXF * 2);
  u16*   xnTg = (u16*)alloc((size_t)DXF * NN * 2);
  u16*   axg  = (u16*)alloc((size_t)NN * NN * 2);
  u16*   hmp  = (u16*)alloc((size_t)JC * 8 * NN * 64 * 2);
  float* xmp  = (float*)alloc((size_t)4 * NN * DXF * 4);
  float* stq  = (float*)alloc((size_t)4 * NN * 4 * 4);
  float* stPd = (float*)alloc((size_t)NN * 4);
  float* hmf  = (float*)alloc((size_t)NN * FD * 4);
  u16*   hfeB = (u16*)alloc((size_t)NN * 544 * 2);
  float* out_hf = (float*)d_out;
  float* out_xm = out_hf + (size_t)NN * FD;

  preproc_k<<<2 * NN + 1536 + 544, 256, 0, stream>>>(
      h, ln_g, ln_b, hnB, x, xnB, Wk, Wq, Wv, wkB, wqB, wvB, Wfc, wfcB);
  xnt_k<<<NN / 16, 256, 0, stream>>>(xnB, xnTg);

  proj3_k<<<dim3(32, 8, 3), 256, 0, stream>>>(hnB, wkB, wqB, wvB, bk, bq, bv, kP, qP, vPT);

  fused_mfma_k<<<dim3(NN / ITI, JC), 512, 0, stream>>>(kP, qP, vPT, xnB, Wm1, bm1, Wm2, bm2,
                                                       hmp, axg, stPd);

  xm_split_k<<<dim3(32, 4, 4), 256, 0, stream>>>(axg, xnTg, xmp, stq);

  epilogue1_k<<<NN, 256, 0, stream>>>(h, x, hmp, xmp, stq, stPd, lnf_g, lnf_b, hmf, hfeB, out_xm);

  fc_gemm_k<<<dim3(64, 16), 256, 0, stream>>>(hfeB, wfcB, bfc, hmf, out_hf);
}

// Round 11
// 180.817 us; speedup vs baseline: 1.0301x; 1.0301x over previous
//
#include <hip/hip_runtime.h>
#include <math.h>

#define NN 2048
#define FD 512
#define DXF 256
#define JC 8
#define CHKJ (NN/JC)      // 256
#define ITI 32
#define JTW 64
#define NIT (CHKJ/JTW)    // 4
#define KC (NN/4)         // 512 (xm split-K chunk)

typedef unsigned short u16;
typedef unsigned int u32;
typedef __attribute__((ext_vector_type(8))) short s16x8;
typedef __attribute__((ext_vector_type(4))) float f32x4;
typedef __attribute__((ext_vector_type(2))) float f32x2;

__device__ __forceinline__ f32x4 MFMA16(s16x8 a, s16x8 b, f32x4 c) {
  return __builtin_amdgcn_mfma_f32_16x16x32_bf16(a, b, c, 0, 0, 0);
}
__device__ __forceinline__ float blo(u32 u) { return __uint_as_float(u << 16); }
__device__ __forceinline__ float bhi(u32 u) { return __uint_as_float(u & 0xffff0000u); }
__device__ __forceinline__ float b2f(u16 v) { return __uint_as_float((u32)v << 16); }
__device__ __forceinline__ u16 bf1(float f) {
  u32 u = __float_as_uint(f);
  u += 0x7fffu + ((u >> 16) & 1u);
  return (u16)(u >> 16);
}
__device__ __forceinline__ u32 pkbf(float a, float b) {
  u32 ua = __float_as_uint(a), ub = __float_as_uint(b);
  ua += 0x7fffu + ((ua >> 16) & 1u);
  ub += 0x7fffu + ((ub >> 16) & 1u);
  return (ua >> 16) | (ub & 0xffff0000u);
}

// ---------- merged preprocessing: ln rows, xn rows, weight converts ----------
__global__ void preproc_k(
    const float* __restrict__ h, const float* __restrict__ ln_g,
    const float* __restrict__ ln_b, u16* __restrict__ hnB,
    const float* __restrict__ x, u16* __restrict__ xnB,
    const float* __restrict__ Wk, const float* __restrict__ Wq,
    const float* __restrict__ Wv, u16* __restrict__ wkB, u16* __restrict__ wqB,
    u16* __restrict__ wvB, const float* __restrict__ Wfc, u16* __restrict__ wfcB) {
  int bid = blockIdx.x, t = threadIdx.x;
  __shared__ float red[4][2];
  if (bid < NN) {
    int r = bid;
    float2 v = ((const float2*)(h + (size_t)r * FD))[t];
    float2 w = make_float2(v.x + v.y, v.x * v.x + v.y * v.y);
#pragma unroll
    for (int o = 32; o > 0; o >>= 1) { w.x += __shfl_xor(w.x, o); w.y += __shfl_xor(w.y, o); }
    if ((t & 63) == 0) { red[t >> 6][0] = w.x; red[t >> 6][1] = w.y; }
    __syncthreads();
    float S  = (red[0][0] + red[1][0]) + (red[2][0] + red[3][0]);
    float SQ = (red[0][1] + red[1][1]) + (red[2][1] + red[3][1]);
    float mean = S * (1.f / FD);
    float var  = SQ * (1.f / FD) - mean * mean;
    float rs = rsqrtf(var + 1e-5f);
    float2 gg = ((const float2*)ln_g)[t], bb = ((const float2*)ln_b)[t];
    float ox = (v.x - mean) * rs * gg.x + bb.x;
    float oy = (v.y - mean) * rs * gg.y + bb.y;
    *(u32*)(hnB + (size_t)r * FD + 2 * t) = pkbf(ox, oy);
  } else if (bid < 2 * NN) {
    int r = bid - NN;
    float v = x[(size_t)r * DXF + t];
    float s = fabsf(v);
#pragma unroll
    for (int o = 32; o > 0; o >>= 1) s += __shfl_xor(s, o);
    if ((t & 63) == 0) red[t >> 6][0] = s;
    __syncthreads();
    float S = (red[0][0] + red[1][0]) + (red[2][0] + red[3][0]);
    float inv = 1.f / fmaxf(S, 1e-12f);
    xnB[(size_t)r * DXF + t] = bf1(v * inv);
  } else if (bid < 2 * NN + 1536) {
    int idx = bid - 2 * NN;
    int z = idx >> 9;
    int i = ((idx & 511) << 8) + t;
    const float* W = (z == 0) ? Wk : (z == 1) ? Wq : Wv;
    u16* O = (z == 0) ? wkB : (z == 1) ? wqB : wvB;
    float2 v = ((const float2*)W)[i];
    ((u32*)O)[i] = pkbf(v.x, v.y);
  } else {
    int i = (bid - (2 * NN + 1536)) * 256 + t;
    if (i < 512 * 272) {
      int r = i / 272, c2 = (i - r * 272) * 2;
      float a = (c2 < 516) ? Wfc[r * 516 + c2] : 0.f;
      float b = (c2 + 1 < 516) ? Wfc[r * 516 + c2 + 1] : 0.f;
      ((u32*)wfcB)[i] = pkbf(a, b);
    }
  }
}

// ---------- transpose xnB [NN][256] -> xnTg [256][NN] ----------
__global__ void xnt_k(const u16* __restrict__ xnB, u16* __restrict__ xnTg) {
  __shared__ u16 tile[16][264];
  int t = threadIdx.x;
  int r0 = blockIdx.x * 16;
#pragma unroll
  for (int s = 0; s < 2; ++s) {
    int c = s * 256 + t;
    int db = c & 31, row = c >> 5;
    *(uint4*)&tile[row][db * 8] = *(const uint4*)(xnB + (size_t)(r0 + row) * DXF + db * 8);
  }
  __syncthreads();
#pragma unroll
  for (int s = 0; s < 2; ++s) {
    int c = s * 256 + t;
    int jb = c & 1, d = c >> 1;
    u32 p[4];
#pragma unroll
    for (int e2 = 0; e2 < 4; ++e2) {
      u16 a = tile[jb * 8 + e2 * 2][d], b = tile[jb * 8 + e2 * 2 + 1][d];
      p[e2] = (u32)a | ((u32)b << 16);
    }
    *(uint4*)(xnTg + (size_t)d * NN + r0 + jb * 8) = make_uint4(p[0], p[1], p[2], p[3]);
  }
}

// ---------- batched projection GEMM: z=0 kP planar, z=1 qP planar, z=2 vPT ----------
__global__ __launch_bounds__(256) void proj3_k(
    const u16* __restrict__ A,
    const u16* __restrict__ W0, const u16* __restrict__ W1, const u16* __restrict__ W2,
    const float* __restrict__ b0, const float* __restrict__ b1, const float* __restrict__ b2,
    u16* __restrict__ kP, u16* __restrict__ qP, u16* __restrict__ vPT) {
  int z = blockIdx.z;
  const u16* B = (z == 0) ? W0 : (z == 1) ? W1 : W2;
  const float* bias = (z == 0) ? b0 : (z == 1) ? b1 : b2;
  int t = threadIdx.x, w = t >> 6, lane = t & 63, g = lane >> 4, li = lane & 15;
  int m0 = blockIdx.x * 64 + (w & 1) * 32;
  int n0 = blockIdx.y * 64 + (w >> 1) * 32;
  f32x4 acc[2][2] = {};
  for (int k0 = 0; k0 < FD; k0 += 32) {
    s16x8 a0 = *(const s16x8*)(A + (size_t)(m0 + li) * FD + k0 + g * 8);
    s16x8 a1 = *(const s16x8*)(A + (size_t)(m0 + 16 + li) * FD + k0 + g * 8);
    s16x8 bA = *(const s16x8*)(B + (size_t)(n0 + li) * FD + k0 + g * 8);
    s16x8 bB = *(const s16x8*)(B + (size_t)(n0 + 16 + li) * FD + k0 + g * 8);
    acc[0][0] = MFMA16(a0, bA, acc[0][0]);
    acc[0][1] = MFMA16(a0, bB, acc[0][1]);
    acc[1][0] = MFMA16(a1, bA, acc[1][0]);
    acc[1][1] = MFMA16(a1, bB, acc[1][1]);
  }
#pragma unroll
  for (int ms = 0; ms < 2; ++ms)
#pragma unroll
    for (int ns = 0; ns < 2; ++ns) {
      int ncol = n0 + ns * 16 + li;
      float bv = bias[ncol];
      if (z < 2) {
        u16* out = z ? qP : kP;
#pragma unroll
        for (int r = 0; r < 4; ++r) {
          int i = m0 + ms * 16 + g * 4 + r;
          out[((size_t)(ncol & 7) * NN + i) * 64 + (ncol >> 3)] = bf1(acc[ms][ns][r] + bv);
        }
      } else {
        u16 e[4];
#pragma unroll
        for (int r = 0; r < 4; ++r) e[r] = bf1(acc[ms][ns][r] + bv);
        u32 p0 = (u32)e[0] | ((u32)e[1] << 16);
        u32 p1 = (u32)e[2] | ((u32)e[3] << 16);
        int ib = m0 + ms * 16 + g * 4;
        *(uint2*)(vPT + ((size_t)((ncol & 7) * 64 + (ncol >> 3))) * NN + ib) =
            make_uint2(p0, p1);
      }
    }
}

// ---------- fc GEMM (32x32 tiles): elu + residual ----------
__global__ __launch_bounds__(256) void fc_gemm_k(
    const u16* __restrict__ A, const u16* __restrict__ B,
    const float* __restrict__ bias, const float* __restrict__ res,
    float* __restrict__ C) {
  int t = threadIdx.x, w = t >> 6, lane = t & 63, g = lane >> 4, li = lane & 15;
  int m0 = blockIdx.x * 32 + (w & 1) * 16;
  int n0 = blockIdx.y * 32 + (w >> 1) * 16;
  f32x4 acc = {};
  for (int k0 = 0; k0 < 544; k0 += 32) {
    s16x8 a0 = *(const s16x8*)(A + (size_t)(m0 + li) * 544 + k0 + g * 8);
    s16x8 b0 = *(const s16x8*)(B + (size_t)(n0 + li) * 544 + k0 + g * 8);
    acc = MFMA16(a0, b0, acc);
  }
  int ncol = n0 + li;
  float bv = bias[ncol];
#pragma unroll
  for (int r = 0; r < 4; ++r) {
    int i = m0 + g * 4 + r;
    float cv = acc[r] + bv;
    cv = (cv > 0.f) ? cv : (expf(cv) - 1.f);
    cv += res[(size_t)i * FD + ncol];
    C[(size_t)i * FD + ncol] = cv;
  }
}

// ---------- xm GEMM split-K + partial row stats of axg ----------
__global__ __launch_bounds__(256) void xm_split_k(
    const u16* __restrict__ axg, const u16* __restrict__ xnTg,
    float* __restrict__ xmp, float* __restrict__ stq) {
  int t = threadIdx.x, w = t >> 6, lane = t & 63, g = lane >> 4, li = lane & 15;
  int m0 = blockIdx.x * 64 + (w & 1) * 32;
  int n0 = blockIdx.y * 64 + (w >> 1) * 32;
  int z = blockIdx.z;
  const int kb = z * KC;
  f32x4 acc[2][2] = {};
  float sab[2] = {0.f, 0.f}, ssu[2] = {0.f, 0.f}, ssq[2] = {0.f, 0.f};
  float smx[2] = {-1e30f, -1e30f};
  const bool do_stats = (blockIdx.y == 0) && ((w >> 1) == 0);
  for (int k0 = 0; k0 < KC; k0 += 32) {
    s16x8 a0 = *(const s16x8*)(axg + (size_t)(m0 + li) * NN + kb + k0 + g * 8);
    s16x8 a1 = *(const s16x8*)(axg + (size_t)(m0 + 16 + li) * NN + kb + k0 + g * 8);
    s16x8 bA = *(const s16x8*)(xnTg + (size_t)(n0 + li) * NN + kb + k0 + g * 8);
    s16x8 bB = *(const s16x8*)(xnTg + (size_t)(n0 + 16 + li) * NN + kb + k0 + g * 8);
    acc[0][0] = MFMA16(a0, bA, acc[0][0]);
    acc[0][1] = MFMA16(a0, bB, acc[0][1]);
    acc[1][0] = MFMA16(a1, bA, acc[1][0]);
    acc[1][1] = MFMA16(a1, bB, acc[1][1]);
    if (do_stats) {
#pragma unroll
      for (int ms = 0; ms < 2; ++ms) {
        u32 pu[4];
        *(s16x8*)pu = ms ? a1 : a0;
#pragma unroll
        for (int q2 = 0; q2 < 4; ++q2) {
          float x0 = blo(pu[q2]), x1 = bhi(pu[q2]);
          sab[ms] += fabsf(x0) + fabsf(x1);
          ssu[ms] += x0 + x1;
          ssq[ms] += x0 * x0 + x1 * x1;
          smx[ms] = fmaxf(smx[ms], fmaxf(x0, x1));
        }
      }
    }
  }
  if (do_stats) {
#pragma unroll
    for (int off = 16; off < 64; off <<= 1) {
#pragma unroll
      for (int ms = 0; ms < 2; ++ms) {
        sab[ms] += __shfl_xor(sab[ms], off);
        ssu[ms] += __shfl_xor(ssu[ms], off);
        ssq[ms] += __shfl_xor(ssq[ms], off);
        smx[ms] = fmaxf(smx[ms], __shfl_xor(smx[ms], off));
      }
    }
    if (g == 0) {
#pragma unroll
      for (int ms = 0; ms < 2; ++ms) {
        size_t base = ((size_t)z * NN + m0 + ms * 16 + li) * 4;
        stq[base + 0] = sab[ms]; stq[base + 1] = ssu[ms];
        stq[base + 2] = ssq[ms]; stq[base + 3] = smx[ms];
      }
    }
  }
#pragma unroll
  for (int ms = 0; ms < 2; ++ms)
#pragma unroll
    for (int ns = 0; ns < 2; ++ns) {
      int ncol = n0 + ns * 16 + li;
#pragma unroll
      for (int r = 0; r < 4; ++r) {
        int i = m0 + ms * 16 + g * 4 + r;
        xmp[(size_t)z * NN * DXF + (size_t)i * DXF + ncol] = acc[ms][ns][r];
      }
    }
}

// ---------- fused pairwise kernel (R6 structure; pk-f32 mixing) ----------
// grid (64, 8); 512 threads = 8 waves. i-tile 32, j-iter 64, 4 iters.
// LDS 80 KB: kI [8][32][128B]^swz (32K) | xnI [32][512B]^swz (16K) | P [8hd][32i][128B]^swz (32K)
// Mixing processes r-values in PAIRS with f32x2 data and SCALAR (SGPR) weights ->
// v_pk_fma_f32, halving mixing VALU issues without VGPR blowup (R5 lesson).
__global__ __launch_bounds__(512, 4) void fused_mfma_k(
    const u16* __restrict__ kP, const u16* __restrict__ qP,
    const u16* __restrict__ vPT, const u16* __restrict__ xnB,
    const float* __restrict__ Wm1, const float* __restrict__ bm1,
    const float* __restrict__ Wm2, const float* __restrict__ bm2,
    u16* __restrict__ hmPart, u16* __restrict__ axg, float* __restrict__ stPd) {
  __shared__ __align__(16) unsigned char L[81920];
  const int O_KI = 0, O_XNI = 32768, O_P = 49152;
  const int t = threadIdx.x, w = t >> 6, lane = t & 63;
  const int g = lane >> 4, li = lane & 15;
  const int i0 = blockIdx.x * ITI, chunk = blockIdx.y;
  const int si = w & 1;                 // i-subtile (scores & PV)
  const int jL = (w >> 1) * 16 + li;    // score j within 64
  const int iRow = si * 16 + li;        // A-frag row

  float W1[8][9], B1v[8];
  float C0, Cax, Cb[8];
  {
    float w2v[8];
#pragma unroll
    for (int o = 0; o < 8; ++o) {
      B1v[o] = bm1[o];
      w2v[o] = Wm2[o];
#pragma unroll
      for (int b3 = 0; b3 < 9; ++b3) W1[o][b3] = Wm1[o * 9 + b3];
    }
    C0 = bm2[0]; Cax = 1.f;
#pragma unroll
    for (int b = 0; b < 8; ++b) Cb[b] = 0.f;
#pragma unroll
    for (int o = 0; o < 8; ++o) {
      C0 += w2v[o] * B1v[o];
      Cax += w2v[o] * W1[o][0];
#pragma unroll
      for (int b = 0; b < 8; ++b) Cb[b] += w2v[o] * W1[o][1 + b];
    }
  }

  // stage kI + xnI once per block (XOR-swizzled)
#pragma unroll
  for (int s = 0; s < 4; ++s) {
    int c = s * 512 + t;
    int yb = c & 7, il = (c >> 3) & 31, b = c >> 8;
    uint4 v = *(const uint4*)(kP + ((size_t)b * NN + i0 + il) * 64 + yb * 8);
    *(uint4*)(L + O_KI + b * 4096 + il * 128 + ((yb ^ (il & 7)) << 4)) = v;
  }
#pragma unroll
  for (int s = 0; s < 2; ++s) {
    int c = s * 512 + t;
    int db = c & 31, il = c >> 5;
    uint4 v = *(const uint4*)(xnB + (size_t)(i0 + il) * DXF + db * 8);
    *(uint4*)(L + O_XNI + il * 512 + ((db ^ (il & 7)) << 4)) = v;
  }
  __syncthreads();

  f32x4 hmA[2][4];
#pragma unroll
  for (int a = 0; a < 2; ++a)
#pragma unroll
    for (int c = 0; c < 4; ++c) hmA[a][c] = (f32x4)(0.f);

  for (int it = 0; it < NIT; ++it) {
    const int j0 = chunk * CHKJ + it * JTW;
    // ---- phase 1: scores (A from LDS, B from global) ----
    f32x4 accS[9];
#pragma unroll
    for (int a = 0; a < 9; ++a) accS[a] = (f32x4)(0.f);
#pragma unroll
    for (int b = 0; b < 8; ++b)
#pragma unroll
      for (int ks = 0; ks < 2; ++ks) {
        int blk = ks * 4 + g;
        s16x8 af = *(const s16x8*)(L + O_KI + b * 4096 + iRow * 128 +
                                   ((blk ^ (iRow & 7)) << 4));
        s16x8 bf = *(const s16x8*)(qP + ((size_t)b * NN + j0 + jL) * 64 + ks * 32 + g * 8);
        accS[b] = MFMA16(af, bf, accS[b]);
      }
#pragma unroll
    for (int ks = 0; ks < 8; ++ks) {
      int blk = ks * 4 + g;
      s16x8 af = *(const s16x8*)(L + O_XNI + iRow * 512 + ((blk ^ (iRow & 7)) << 4));
      s16x8 bf = *(const s16x8*)(xnB + (size_t)(j0 + jL) * DXF + ks * 32 + g * 8);
      accS[8] = MFMA16(af, bf, accS[8]);
    }
    __syncthreads();  // previous PV done reading P
    // ---- mixing (pk-f32, scalar weights) + softmax + P/axn ----
#pragma unroll
    for (int rp = 0; rp < 2; ++rp) {
      f32x2 sbp[8], axp;
#pragma unroll
      for (int b = 0; b < 8; ++b) {
        sbp[b][0] = accS[b][2 * rp]; sbp[b][1] = accS[b][2 * rp + 1];
      }
      axp[0] = accS[8][2 * rp]; axp[1] = accS[8][2 * rp + 1];
      f32x2 mp[8];
#pragma unroll
      for (int o = 0; o < 8; ++o) mp[o] = B1v[o] + W1[o][0] * axp;
#pragma unroll
      for (int b = 0; b < 8; ++b) {
#pragma unroll
        for (int o = 0; o < 8; ++o) mp[o] += W1[o][1 + b] * sbp[b];
      }
      f32x2 axnp = C0 + Cax * axp;
#pragma unroll
      for (int b = 0; b < 8; ++b) axnp += Cb[b] * sbp[b];
      f32x2 mxp = __builtin_elementwise_max(
          __builtin_elementwise_max(__builtin_elementwise_max(mp[0], mp[1]),
                                    __builtin_elementwise_max(mp[2], mp[3])),
          __builtin_elementwise_max(__builtin_elementwise_max(mp[4], mp[5]),
                                    __builtin_elementwise_max(mp[6], mp[7])));
#pragma unroll
      for (int rr = 0; rr < 2; ++rr) {
        const int r = 2 * rp + rr;
        const float axn = axnp[rr];
        const int iL2 = si * 16 + g * 4 + r;
        const int iG = i0 + iL2, jG = j0 + jL;
        axg[(size_t)iG * NN + jG] = bf1(axn);
        if (iG == jG) stPd[iG] = axn;
        const float mx = mxp[rr];
        float es[8], esum = 0.f;
#pragma unroll
        for (int o = 0; o < 8; ++o) { es[o] = __expf(mp[o][rr] - mx); esum += es[o]; }
        float inv = 1.f / esum;
        const int base = iL2 * 128 + (((jL >> 3) ^ (iL2 & 7)) << 4) + (jL & 7) * 2;
#pragma unroll
        for (int b = 0; b < 8; ++b)
          *(u16*)(L + O_P + b * 4096 + base) = bf1(es[b] * inv);
      }
    }
    __syncthreads();  // P visible
    // ---- phase 2: PV (A=P from LDS, B=vPT from global) ----
#pragma unroll
    for (int hh = 0; hh < 2; ++hh) {
      const int hd = (w >> 1) * 2 + hh;
#pragma unroll
      for (int kb = 0; kb < 2; ++kb) {
        const int prow = si * 16 + li;
        s16x8 pa = *(const s16x8*)(L + O_P + hd * 4096 + prow * 128 +
                                   (((kb * 4 + g) ^ (prow & 7)) << 4));
#pragma unroll
        for (int zt = 0; zt < 4; ++zt) {
          s16x8 vf = *(const s16x8*)(vPT + ((size_t)hd * 64 + zt * 16 + li) * NN +
                                     j0 + kb * 32 + g * 8);
          hmA[hh][zt] = MFMA16(pa, vf, hmA[hh][zt]);
        }
      }
    }
  }
  // ---- write hm partials (bf16) ----
#pragma unroll
  for (int hh = 0; hh < 2; ++hh) {
    const int hd = (w >> 1) * 2 + hh;
#pragma unroll
    for (int zt = 0; zt < 4; ++zt)
#pragma unroll
      for (int r = 0; r < 4; ++r) {
        int i = i0 + si * 16 + g * 4 + r;
        int z = zt * 16 + li;
        hmPart[((size_t)(chunk * 8 + hd) * NN + i) * 64 + z] = bf1(hmA[hh][zt][r]);
      }
  }
}

// ---------- epilogue ----------
__global__ void epilogue1_k(
    const float* __restrict__ h, const float* __restrict__ x,
    const u16* __restrict__ hmp, const float* __restrict__ xmp,
    const float* __restrict__ stq, const float* __restrict__ stPd,
    const float* __restrict__ lnf_g, const float* __restrict__ lnf_b,
    float* __restrict__ hmf, u16* __restrict__ hfeB, float* __restrict__ out_xm) {
  int r = blockIdx.x, t = threadIdx.x;
  int c0 = 2 * t, c1 = c0 + 1;
  float2 acc = ((const float2*)(h + (size_t)r * FD))[t];
#pragma unroll
  for (int ch = 0; ch < JC; ++ch) {
    acc.x += b2f(hmp[((size_t)(ch * 8 + (c0 & 7)) * NN + r) * 64 + (c0 >> 3)]);
    acc.y += b2f(hmp[((size_t)(ch * 8 + (c1 & 7)) * NN + r) * 64 + (c1 >> 3)]);
  }
  ((float2*)(hmf + (size_t)r * FD))[t] = acc;
  float2 w = make_float2(acc.x + acc.y, acc.x * acc.x + acc.y * acc.y);
#pragma unroll
  for (int o = 32; o > 0; o >>= 1) { w.x += __shfl_xor(w.x, o); w.y += __shfl_xor(w.y, o); }
  __shared__ float red[4][2];
  __shared__ float s_inv;
  if ((t & 63) == 0) { red[t >> 6][0] = w.x; red[t >> 6][1] = w.y; }
  __syncthreads();
  float S  = (red[0][0] + red[1][0]) + (red[2][0] + red[3][0]);
  float SQ = (red[0][1] + red[1][1]) + (red[2][1] + red[3][1]);
  float mean = S * (1.f / FD);
  float var  = SQ * (1.f / FD) - mean * mean;
  float rs = rsqrtf(var + 1e-5f);
  float2 g2 = ((const float2*)lnf_g)[t], b2 = ((const float2*)lnf_b)[t];
  float ox = (acc.x - mean) * rs * g2.x + b2.x;
  float oy = (acc.y - mean) * rs * g2.y + b2.y;
  *(u32*)(hfeB + (size_t)r * 544 + c0) = pkbf(ox, oy);
  if (t == 0) {
    float sab = 0.f, ssu = 0.f, ssq = 0.f, smx = -1e30f;
#pragma unroll
    for (int c = 0; c < 4; ++c) {
      size_t b = ((size_t)c * NN + r) * 4;
      sab += stq[b + 0]; ssu += stq[b + 1]; ssq += stq[b + 2];
      smx = fmaxf(smx, stq[b + 3]);
    }
    float diag = stPd[r];
    float L1 = fmaxf(sab, 1e-12f);
    float inv = 1.f / L1;
    float stdv = sqrtf(fmaxf((ssq - ssu * ssu * (1.f / 2048.f)) * (1.f / 2047.f), 0.f)) * inv;
    u16* he = hfeB + (size_t)r * 544;
    he[512] = bf1(diag * inv); he[513] = bf1(ssu * inv);
    he[514] = bf1(stdv);       he[515] = bf1(smx * inv);
    s_inv = inv;
  }
  if (t < 14) *(u32*)(hfeB + (size_t)r * 544 + 516 + 2 * t) = 0;
  __syncthreads();
  float inv = s_inv;
  float xv = xmp[(size_t)r * DXF + t] + xmp[(size_t)NN * DXF + (size_t)r * DXF + t] +
             xmp[2 * (size_t)NN * DXF + (size_t)r * DXF + t] +
             xmp[3 * (size_t)NN * DXF + (size_t)r * DXF + t];
  out_xm[(size_t)r * DXF + t] = xv * inv + x[(size_t)r * DXF + t];
}

extern "C" void kernel_launch(void* const* d_in, const int* in_sizes, int n_in,
                              void* d_out, int out_size, void* d_ws, size_t ws_size,
                              hipStream_t stream) {
  (void)in_sizes; (void)n_in; (void)out_size; (void)ws_size;
  const float* h    = (const float*)d_in[0];
  const float* x    = (const float*)d_in[1];
  const float* ln_g = (const float*)d_in[2];
  const float* ln_b = (const float*)d_in[3];
  const float* Wk   = (const float*)d_in[4];
  const float* bk   = (const float*)d_in[5];
  const float* Wq   = (const float*)d_in[6];
  const float* bq   = (const float*)d_in[7];
  const float* Wv   = (const float*)d_in[8];
  const float* bv   = (const float*)d_in[9];
  const float* Wm1  = (const float*)d_in[10];
  const float* bm1  = (const float*)d_in[11];
  const float* Wm2  = (const float*)d_in[12];
  const float* bm2  = (const float*)d_in[13];
  const float* lnf_g = (const float*)d_in[14];
  const float* lnf_b = (const float*)d_in[15];
  const float* Wfc  = (const float*)d_in[16];
  const float* bfc  = (const float*)d_in[17];

  char* wsb = (char*)d_ws;
  size_t off = 0;
  auto alloc = [&](size_t bytes) { char* p = wsb + off; off += (bytes + 255) & ~(size_t)255; return p; };
  u16*   hnB  = (u16*)alloc((size_t)NN * FD * 2);
  u16*   wkB  = (u16*)alloc((size_t)FD * FD * 2);
  u16*   wqB  = (u16*)alloc((size_t)FD * FD * 2);
  u16*   wvB  = (u16*)alloc((size_t)FD * FD * 2);
  u16*   wfcB = (u16*)alloc((size_t)512 * 544 * 2);
  u16*   kP   = (u16*)alloc((size_t)8 * NN * 64 * 2);
  u16*   qP   = (u16*)alloc((size_t)8 * NN * 64 * 2);
  u16*   vPT  = (u16*)alloc((size_t)8 * 64 * NN * 2);
  u16*   xnB  = (u16*)alloc((size_t)NN * DXF * 2);
  u16*   xnTg = (u16*)alloc((size_t)DXF * NN * 2);
  u16*   axg  = (u16*)alloc((size_t)NN * NN * 2);
  u16*   hmp  = (u16*)alloc((size_t)JC * 8 * NN * 64 * 2);
  float* xmp  = (float*)alloc((size_t)4 * NN * DXF * 4);
  float* stq  = (float*)alloc((size_t)4 * NN * 4 * 4);
  float* stPd = (float*)alloc((size_t)NN * 4);
  float* hmf  = (float*)alloc((size_t)NN * FD * 4);
  u16*   hfeB = (u16*)alloc((size_t)NN * 544 * 2);
  float* out_hf = (float*)d_out;
  float* out_xm = out_hf + (size_t)NN * FD;

  preproc_k<<<2 * NN + 1536 + 544, 256, 0, stream>>>(
      h, ln_g, ln_b, hnB, x, xnB, Wk, Wq, Wv, wkB, wqB, wvB, Wfc, wfcB);
  xnt_k<<<NN / 16, 256, 0, stream>>>(xnB, xnTg);

  proj3_k<<<dim3(32, 8, 3), 256, 0, stream>>>(hnB, wkB, wqB, wvB, bk, bq, bv, kP, qP, vPT);

  fused_mfma_k<<<dim3(NN / ITI, JC), 512, 0, stream>>>(kP, qP, vPT, xnB, Wm1, bm1, Wm2, bm2,
                                                       hmp, axg, stPd);

  xm_split_k<<<dim3(32, 4, 4), 256, 0, stream>>>(axg, xnTg, xmp, stq);

  epilogue1_k<<<NN, 256, 0, stream>>>(h, x, hmp, xmp, stq, stPd, lnf_g, lnf_b, hmf, hfeB, out_xm);

  fc_gemm_k<<<dim3(64, 16), 256, 0, stream>>>(hfeB, wfcB, bfc, hmf, out_hf);
}

// Round 12
// 159.667 us; speedup vs baseline: 1.1665x; 1.1325x over previous
//
#include <hip/hip_runtime.h>
#include <math.h>

#define NN 2048
#define FD 512
#define DXF 256
#define JC 8
#define CHKJ (NN/JC)      // 256
#define ITI 32
#define JTW 64
#define NIT (CHKJ/JTW)    // 4
#define KC (NN/4)         // 512 (xm split-K chunk)

typedef unsigned short u16;
typedef unsigned int u32;
typedef __attribute__((ext_vector_type(8))) short s16x8;
typedef __attribute__((ext_vector_type(4))) float f32x4;

__device__ __forceinline__ f32x4 MFMA16(s16x8 a, s16x8 b, f32x4 c) {
  return __builtin_amdgcn_mfma_f32_16x16x32_bf16(a, b, c, 0, 0, 0);
}
__device__ __forceinline__ float blo(u32 u) { return __uint_as_float(u << 16); }
__device__ __forceinline__ float bhi(u32 u) { return __uint_as_float(u & 0xffff0000u); }
__device__ __forceinline__ float b2f(u16 v) { return __uint_as_float((u32)v << 16); }
__device__ __forceinline__ u16 bf1(float f) {
  u32 u = __float_as_uint(f);
  u += 0x7fffu + ((u >> 16) & 1u);
  return (u16)(u >> 16);
}
__device__ __forceinline__ u32 pkbf(float a, float b) {
  u32 ua = __float_as_uint(a), ub = __float_as_uint(b);
  ua += 0x7fffu + ((ua >> 16) & 1u);
  ub += 0x7fffu + ((ub >> 16) & 1u);
  return (ua >> 16) | (ub & 0xffff0000u);
}

// ---------- merged preprocessing: ln rows, xn rows, weight converts ----------
__global__ void preproc_k(
    const float* __restrict__ h, const float* __restrict__ ln_g,
    const float* __restrict__ ln_b, u16* __restrict__ hnB,
    const float* __restrict__ x, u16* __restrict__ xnB,
    const float* __restrict__ Wk, const float* __restrict__ Wq,
    const float* __restrict__ Wv, u16* __restrict__ wkB, u16* __restrict__ wqB,
    u16* __restrict__ wvB, const float* __restrict__ Wfc, u16* __restrict__ wfcB) {
  int bid = blockIdx.x, t = threadIdx.x;
  __shared__ float red[4][2];
  if (bid < NN) {
    int r = bid;
    float2 v = ((const float2*)(h + (size_t)r * FD))[t];
    float2 w = make_float2(v.x + v.y, v.x * v.x + v.y * v.y);
#pragma unroll
    for (int o = 32; o > 0; o >>= 1) { w.x += __shfl_xor(w.x, o); w.y += __shfl_xor(w.y, o); }
    if ((t & 63) == 0) { red[t >> 6][0] = w.x; red[t >> 6][1] = w.y; }
    __syncthreads();
    float S  = (red[0][0] + red[1][0]) + (red[2][0] + red[3][0]);
    float SQ = (red[0][1] + red[1][1]) + (red[2][1] + red[3][1]);
    float mean = S * (1.f / FD);
    float var  = SQ * (1.f / FD) - mean * mean;
    float rs = rsqrtf(var + 1e-5f);
    float2 gg = ((const float2*)ln_g)[t], bb = ((const float2*)ln_b)[t];
    float ox = (v.x - mean) * rs * gg.x + bb.x;
    float oy = (v.y - mean) * rs * gg.y + bb.y;
    *(u32*)(hnB + (size_t)r * FD + 2 * t) = pkbf(ox, oy);
  } else if (bid < 2 * NN) {
    int r = bid - NN;
    float v = x[(size_t)r * DXF + t];
    float s = fabsf(v);
#pragma unroll
    for (int o = 32; o > 0; o >>= 1) s += __shfl_xor(s, o);
    if ((t & 63) == 0) red[t >> 6][0] = s;
    __syncthreads();
    float S = (red[0][0] + red[1][0]) + (red[2][0] + red[3][0]);
    float inv = 1.f / fmaxf(S, 1e-12f);
    xnB[(size_t)r * DXF + t] = bf1(v * inv);
  } else if (bid < 2 * NN + 1536) {
    int idx = bid - 2 * NN;
    int z = idx >> 9;
    int i = ((idx & 511) << 8) + t;
    const float* W = (z == 0) ? Wk : (z == 1) ? Wq : Wv;
    u16* O = (z == 0) ? wkB : (z == 1) ? wqB : wvB;
    float2 v = ((const float2*)W)[i];
    ((u32*)O)[i] = pkbf(v.x, v.y);
  } else {
    int i = (bid - (2 * NN + 1536)) * 256 + t;
    if (i < 512 * 272) {
      int r = i / 272, c2 = (i - r * 272) * 2;
      float a = (c2 < 516) ? Wfc[r * 516 + c2] : 0.f;
      float b = (c2 + 1 < 516) ? Wfc[r * 516 + c2 + 1] : 0.f;
      ((u32*)wfcB)[i] = pkbf(a, b);
    }
  }
}

// ---------- transpose xnB [NN][256] -> xnTg [256][NN] ----------
__global__ void xnt_k(const u16* __restrict__ xnB, u16* __restrict__ xnTg) {
  __shared__ u16 tile[16][264];
  int t = threadIdx.x;
  int r0 = blockIdx.x * 16;
#pragma unroll
  for (int s = 0; s < 2; ++s) {
    int c = s * 256 + t;
    int db = c & 31, row = c >> 5;
    *(uint4*)&tile[row][db * 8] = *(const uint4*)(xnB + (size_t)(r0 + row) * DXF + db * 8);
  }
  __syncthreads();
#pragma unroll
  for (int s = 0; s < 2; ++s) {
    int c = s * 256 + t;
    int jb = c & 1, d = c >> 1;
    u32 p[4];
#pragma unroll
    for (int e2 = 0; e2 < 4; ++e2) {
      u16 a = tile[jb * 8 + e2 * 2][d], b = tile[jb * 8 + e2 * 2 + 1][d];
      p[e2] = (u32)a | ((u32)b << 16);
    }
    *(uint4*)(xnTg + (size_t)d * NN + r0 + jb * 8) = make_uint4(p[0], p[1], p[2], p[3]);
  }
}

// ---------- batched projection GEMM: z=0 kP planar, z=1 qP planar, z=2 vPT ----------
__global__ __launch_bounds__(256) void proj3_k(
    const u16* __restrict__ A,
    const u16* __restrict__ W0, const u16* __restrict__ W1, const u16* __restrict__ W2,
    const float* __restrict__ b0, const float* __restrict__ b1, const float* __restrict__ b2,
    u16* __restrict__ kP, u16* __restrict__ qP, u16* __restrict__ vPT) {
  int z = blockIdx.z;
  const u16* B = (z == 0) ? W0 : (z == 1) ? W1 : W2;
  const float* bias = (z == 0) ? b0 : (z == 1) ? b1 : b2;
  int t = threadIdx.x, w = t >> 6, lane = t & 63, g = lane >> 4, li = lane & 15;
  int m0 = blockIdx.x * 64 + (w & 1) * 32;
  int n0 = blockIdx.y * 64 + (w >> 1) * 32;
  f32x4 acc[2][2] = {};
  for (int k0 = 0; k0 < FD; k0 += 32) {
    s16x8 a0 = *(const s16x8*)(A + (size_t)(m0 + li) * FD + k0 + g * 8);
    s16x8 a1 = *(const s16x8*)(A + (size_t)(m0 + 16 + li) * FD + k0 + g * 8);
    s16x8 bA = *(const s16x8*)(B + (size_t)(n0 + li) * FD + k0 + g * 8);
    s16x8 bB = *(const s16x8*)(B + (size_t)(n0 + 16 + li) * FD + k0 + g * 8);
    acc[0][0] = MFMA16(a0, bA, acc[0][0]);
    acc[0][1] = MFMA16(a0, bB, acc[0][1]);
    acc[1][0] = MFMA16(a1, bA, acc[1][0]);
    acc[1][1] = MFMA16(a1, bB, acc[1][1]);
  }
#pragma unroll
  for (int ms = 0; ms < 2; ++ms)
#pragma unroll
    for (int ns = 0; ns < 2; ++ns) {
      int ncol = n0 + ns * 16 + li;
      float bv = bias[ncol];
      if (z < 2) {
        u16* out = z ? qP : kP;
#pragma unroll
        for (int r = 0; r < 4; ++r) {
          int i = m0 + ms * 16 + g * 4 + r;
          out[((size_t)(ncol & 7) * NN + i) * 64 + (ncol >> 3)] = bf1(acc[ms][ns][r] + bv);
        }
      } else {
        u16 e[4];
#pragma unroll
        for (int r = 0; r < 4; ++r) e[r] = bf1(acc[ms][ns][r] + bv);
        u32 p0 = (u32)e[0] | ((u32)e[1] << 16);
        u32 p1 = (u32)e[2] | ((u32)e[3] << 16);
        int ib = m0 + ms * 16 + g * 4;
        *(uint2*)(vPT + ((size_t)((ncol & 7) * 64 + (ncol >> 3))) * NN + ib) =
            make_uint2(p0, p1);
      }
    }
}

// ---------- fc GEMM (32x32 tiles): elu + residual ----------
__global__ __launch_bounds__(256) void fc_gemm_k(
    const u16* __restrict__ A, const u16* __restrict__ B,
    const float* __restrict__ bias, const float* __restrict__ res,
    float* __restrict__ C) {
  int t = threadIdx.x, w = t >> 6, lane = t & 63, g = lane >> 4, li = lane & 15;
  int m0 = blockIdx.x * 32 + (w & 1) * 16;
  int n0 = blockIdx.y * 32 + (w >> 1) * 16;
  f32x4 acc = {};
  for (int k0 = 0; k0 < 544; k0 += 32) {
    s16x8 a0 = *(const s16x8*)(A + (size_t)(m0 + li) * 544 + k0 + g * 8);
    s16x8 b0 = *(const s16x8*)(B + (size_t)(n0 + li) * 544 + k0 + g * 8);
    acc = MFMA16(a0, b0, acc);
  }
  int ncol = n0 + li;
  float bv = bias[ncol];
#pragma unroll
  for (int r = 0; r < 4; ++r) {
    int i = m0 + g * 4 + r;
    float cv = acc[r] + bv;
    cv = (cv > 0.f) ? cv : (expf(cv) - 1.f);
    cv += res[(size_t)i * FD + ncol];
    C[(size_t)i * FD + ncol] = cv;
  }
}

// ---------- xm GEMM split-K + partial row stats of axg ----------
__global__ __launch_bounds__(256) void xm_split_k(
    const u16* __restrict__ axg, const u16* __restrict__ xnTg,
    float* __restrict__ xmp, float* __restrict__ stq) {
  int t = threadIdx.x, w = t >> 6, lane = t & 63, g = lane >> 4, li = lane & 15;
  int m0 = blockIdx.x * 64 + (w & 1) * 32;
  int n0 = blockIdx.y * 64 + (w >> 1) * 32;
  int z = blockIdx.z;
  const int kb = z * KC;
  f32x4 acc[2][2] = {};
  float sab[2] = {0.f, 0.f}, ssu[2] = {0.f, 0.f}, ssq[2] = {0.f, 0.f};
  float smx[2] = {-1e30f, -1e30f};
  const bool do_stats = (blockIdx.y == 0) && ((w >> 1) == 0);
  for (int k0 = 0; k0 < KC; k0 += 32) {
    s16x8 a0 = *(const s16x8*)(axg + (size_t)(m0 + li) * NN + kb + k0 + g * 8);
    s16x8 a1 = *(const s16x8*)(axg + (size_t)(m0 + 16 + li) * NN + kb + k0 + g * 8);
    s16x8 bA = *(const s16x8*)(xnTg + (size_t)(n0 + li) * NN + kb + k0 + g * 8);
    s16x8 bB = *(const s16x8*)(xnTg + (size_t)(n0 + 16 + li) * NN + kb + k0 + g * 8);
    acc[0][0] = MFMA16(a0, bA, acc[0][0]);
    acc[0][1] = MFMA16(a0, bB, acc[0][1]);
    acc[1][0] = MFMA16(a1, bA, acc[1][0]);
    acc[1][1] = MFMA16(a1, bB, acc[1][1]);
    if (do_stats) {
#pragma unroll
      for (int ms = 0; ms < 2; ++ms) {
        u32 pu[4];
        *(s16x8*)pu = ms ? a1 : a0;
#pragma unroll
        for (int q2 = 0; q2 < 4; ++q2) {
          float x0 = blo(pu[q2]), x1 = bhi(pu[q2]);
          sab[ms] += fabsf(x0) + fabsf(x1);
          ssu[ms] += x0 + x1;
          ssq[ms] += x0 * x0 + x1 * x1;
          smx[ms] = fmaxf(smx[ms], fmaxf(x0, x1));
        }
      }
    }
  }
  if (do_stats) {
#pragma unroll
    for (int off = 16; off < 64; off <<= 1) {
#pragma unroll
      for (int ms = 0; ms < 2; ++ms) {
        sab[ms] += __shfl_xor(sab[ms], off);
        ssu[ms] += __shfl_xor(ssu[ms], off);
        ssq[ms] += __shfl_xor(ssq[ms], off);
        smx[ms] = fmaxf(smx[ms], __shfl_xor(smx[ms], off));
      }
    }
    if (g == 0) {
#pragma unroll
      for (int ms = 0; ms < 2; ++ms) {
        size_t base = ((size_t)z * NN + m0 + ms * 16 + li) * 4;
        stq[base + 0] = sab[ms]; stq[base + 1] = ssu[ms];
        stq[base + 2] = ssq[ms]; stq[base + 3] = smx[ms];
      }
    }
  }
#pragma unroll
  for (int ms = 0; ms < 2; ++ms)
#pragma unroll
    for (int ns = 0; ns < 2; ++ns) {
      int ncol = n0 + ns * 16 + li;
#pragma unroll
      for (int r = 0; r < 4; ++r) {
        int i = m0 + ms * 16 + g * 4 + r;
        xmp[(size_t)z * NN * DXF + (size_t)i * DXF + ncol] = acc[ms][ns][r];
      }
    }
}

// ---------- fused pairwise kernel (R6 + explicit V register prefetch) ----------
// grid (64, 8); 512 threads = 8 waves. i-tile 32, j-iter 64, 4 iters.
// LDS 80 KB: kI [8][32][128B]^swz (32K) | xnI [32][512B]^swz (16K) | P [8hd][32i][128B]^swz (32K)
// V fragments for the CURRENT iter are loaded to registers BEFORE/INSIDE the ~1000-cycle
// softmax VALU block, so their L2/HBM latency hides under softmax; consumed after barrier.
__global__ __launch_bounds__(512, 2) void fused_mfma_k(
    const u16* __restrict__ kP, const u16* __restrict__ qP,
    const u16* __restrict__ vPT, const u16* __restrict__ xnB,
    const float* __restrict__ Wm1, const float* __restrict__ bm1,
    const float* __restrict__ Wm2, const float* __restrict__ bm2,
    u16* __restrict__ hmPart, u16* __restrict__ axg, float* __restrict__ stPd) {
  __shared__ __align__(16) unsigned char L[81920];
  const int O_KI = 0, O_XNI = 32768, O_P = 49152;
  const int t = threadIdx.x, w = t >> 6, lane = t & 63;
  const int g = lane >> 4, li = lane & 15;
  const int i0 = blockIdx.x * ITI, chunk = blockIdx.y;
  const int si = w & 1;                 // i-subtile (scores & PV)
  const int jL = (w >> 1) * 16 + li;    // score j within 64
  const int iRow = si * 16 + li;        // A-frag row
  const int prow = si * 16 + li;

  float W1[8][9], B1v[8], w2v[8];
#pragma unroll
  for (int o = 0; o < 8; ++o) {
    B1v[o] = bm1[o];
    w2v[o] = Wm2[o];
#pragma unroll
    for (int b3 = 0; b3 < 9; ++b3) W1[o][b3] = Wm1[o * 9 + b3];
  }
  const float b2v = bm2[0];

  // stage kI + xnI once per block (XOR-swizzled)
#pragma unroll
  for (int s = 0; s < 4; ++s) {
    int c = s * 512 + t;
    int yb = c & 7, il = (c >> 3) & 31, b = c >> 8;
    uint4 v = *(const uint4*)(kP + ((size_t)b * NN + i0 + il) * 64 + yb * 8);
    *(uint4*)(L + O_KI + b * 4096 + il * 128 + ((yb ^ (il & 7)) << 4)) = v;
  }
#pragma unroll
  for (int s = 0; s < 2; ++s) {
    int c = s * 512 + t;
    int db = c & 31, il = c >> 5;
    uint4 v = *(const uint4*)(xnB + (size_t)(i0 + il) * DXF + db * 8);
    *(uint4*)(L + O_XNI + il * 512 + ((db ^ (il & 7)) << 4)) = v;
  }
  __syncthreads();

  f32x4 hmA[2][4];
#pragma unroll
  for (int a = 0; a < 2; ++a)
#pragma unroll
    for (int c = 0; c < 4; ++c) hmA[a][c] = (f32x4)(0.f);

  for (int it = 0; it < NIT; ++it) {
    const int j0 = chunk * CHKJ + it * JTW;
    // ---- phase 1: scores (A from LDS, B from global) ----
    f32x4 accS[9];
#pragma unroll
    for (int a = 0; a < 9; ++a) accS[a] = (f32x4)(0.f);
#pragma unroll
    for (int b = 0; b < 8; ++b)
#pragma unroll
      for (int ks = 0; ks < 2; ++ks) {
        int blk = ks * 4 + g;
        s16x8 af = *(const s16x8*)(L + O_KI + b * 4096 + iRow * 128 +
                                   ((blk ^ (iRow & 7)) << 4));
        s16x8 bf = *(const s16x8*)(qP + ((size_t)b * NN + j0 + jL) * 64 + ks * 32 + g * 8);
        accS[b] = MFMA16(af, bf, accS[b]);
      }
#pragma unroll
    for (int ks = 0; ks < 8; ++ks) {
      int blk = ks * 4 + g;
      s16x8 af = *(const s16x8*)(L + O_XNI + iRow * 512 + ((blk ^ (iRow & 7)) << 4));
      s16x8 bf = *(const s16x8*)(xnB + (size_t)(j0 + jL) * DXF + ks * 32 + g * 8);
      accS[8] = MFMA16(af, bf, accS[8]);
    }
    // ---- V prefetch (hh=0 half): issue before softmax; latency hides under VALU ----
    s16x8 vf0[2][4];
#pragma unroll
    for (int kb = 0; kb < 2; ++kb)
#pragma unroll
      for (int zt = 0; zt < 4; ++zt)
        vf0[kb][zt] = *(const s16x8*)(vPT + ((size_t)((w >> 1) * 2 + 0) * 64 + zt * 16 + li) * NN +
                                      j0 + kb * 32 + g * 8);
    __syncthreads();  // previous PV done reading P
    // ---- mixing + softmax + P/axn (R6 scalar form) ----
#pragma unroll
    for (int r = 0; r < 4; ++r) {
      float sb[8];
#pragma unroll
      for (int b = 0; b < 8; ++b) sb[b] = accS[b][r];
      float ax = accS[8][r];
      float m[8];
#pragma unroll
      for (int o = 0; o < 8; ++o) {
        float a = B1v[o] + W1[o][0] * ax;
#pragma unroll
        for (int b = 0; b < 8; ++b) a += W1[o][1 + b] * sb[b];
        m[o] = a;
      }
      float axn = b2v + ax;
#pragma unroll
      for (int o = 0; o < 8; ++o) axn += w2v[o] * m[o];
      const int iL2 = si * 16 + g * 4 + r;
      const int iG = i0 + iL2, jG = j0 + jL;
      axg[(size_t)iG * NN + jG] = bf1(axn);
      if (iG == jG) stPd[iG] = axn;
      float mx = m[0];
#pragma unroll
      for (int o = 1; o < 8; ++o) mx = fmaxf(mx, m[o]);
      float es[8], esum = 0.f;
#pragma unroll
      for (int o = 0; o < 8; ++o) { es[o] = __expf(m[o] - mx); esum += es[o]; }
      float inv = 1.f / esum;
      const int base = iL2 * 128 + (((jL >> 3) ^ (iL2 & 7)) << 4) + (jL & 7) * 2;
#pragma unroll
      for (int b = 0; b < 8; ++b)
        *(u16*)(L + O_P + b * 4096 + base) = bf1(es[b] * inv);
    }
    // ---- V prefetch (hh=1 half): accS now dead, reuse its registers ----
    s16x8 vf1[2][4];
#pragma unroll
    for (int kb = 0; kb < 2; ++kb)
#pragma unroll
      for (int zt = 0; zt < 4; ++zt)
        vf1[kb][zt] = *(const s16x8*)(vPT + ((size_t)((w >> 1) * 2 + 1) * 64 + zt * 16 + li) * NN +
                                      j0 + kb * 32 + g * 8);
    __syncthreads();  // P visible
    // ---- phase 2: PV (A=P from LDS, B=prefetched registers) ----
#pragma unroll
    for (int hh = 0; hh < 2; ++hh) {
      const int hd = (w >> 1) * 2 + hh;
#pragma unroll
      for (int kb = 0; kb < 2; ++kb) {
        s16x8 pa = *(const s16x8*)(L + O_P + hd * 4096 + prow * 128 +
                                   (((kb * 4 + g) ^ (prow & 7)) << 4));
#pragma unroll
        for (int zt = 0; zt < 4; ++zt) {
          s16x8 vf = hh ? vf1[kb][zt] : vf0[kb][zt];
          hmA[hh][zt] = MFMA16(pa, vf, hmA[hh][zt]);
        }
      }
    }
  }
  // ---- write hm partials (bf16) ----
#pragma unroll
  for (int hh = 0; hh < 2; ++hh) {
    const int hd = (w >> 1) * 2 + hh;
#pragma unroll
    for (int zt = 0; zt < 4; ++zt)
#pragma unroll
      for (int r = 0; r < 4; ++r) {
        int i = i0 + si * 16 + g * 4 + r;
        int z = zt * 16 + li;
        hmPart[((size_t)(chunk * 8 + hd) * NN + i) * 64 + z] = bf1(hmA[hh][zt][r]);
      }
  }
}

// ---------- epilogue ----------
__global__ void epilogue1_k(
    const float* __restrict__ h, const float* __restrict__ x,
    const u16* __restrict__ hmp, const float* __restrict__ xmp,
    const float* __restrict__ stq, const float* __restrict__ stPd,
    const float* __restrict__ lnf_g, const float* __restrict__ lnf_b,
    float* __restrict__ hmf, u16* __restrict__ hfeB, float* __restrict__ out_xm) {
  int r = blockIdx.x, t = threadIdx.x;
  int c0 = 2 * t, c1 = c0 + 1;
  float2 acc = ((const float2*)(h + (size_t)r * FD))[t];
#pragma unroll
  for (int ch = 0; ch < JC; ++ch) {
    acc.x += b2f(hmp[((size_t)(ch * 8 + (c0 & 7)) * NN + r) * 64 + (c0 >> 3)]);
    acc.y += b2f(hmp[((size_t)(ch * 8 + (c1 & 7)) * NN + r) * 64 + (c1 >> 3)]);
  }
  ((float2*)(hmf + (size_t)r * FD))[t] = acc;
  float2 w = make_float2(acc.x + acc.y, acc.x * acc.x + acc.y * acc.y);
#pragma unroll
  for (int o = 32; o > 0; o >>= 1) { w.x += __shfl_xor(w.x, o); w.y += __shfl_xor(w.y, o); }
  __shared__ float red[4][2];
  __shared__ float s_inv;
  if ((t & 63) == 0) { red[t >> 6][0] = w.x; red[t >> 6][1] = w.y; }
  __syncthreads();
  float S  = (red[0][0] + red[1][0]) + (red[2][0] + red[3][0]);
  float SQ = (red[0][1] + red[1][1]) + (red[2][1] + red[3][1]);
  float mean = S * (1.f / FD);
  float var  = SQ * (1.f / FD) - mean * mean;
  float rs = rsqrtf(var + 1e-5f);
  float2 g2 = ((const float2*)lnf_g)[t], b2 = ((const float2*)lnf_b)[t];
  float ox = (acc.x - mean) * rs * g2.x + b2.x;
  float oy = (acc.y - mean) * rs * g2.y + b2.y;
  *(u32*)(hfeB + (size_t)r * 544 + c0) = pkbf(ox, oy);
  if (t == 0) {
    float sab = 0.f, ssu = 0.f, ssq = 0.f, smx = -1e30f;
#pragma unroll
    for (int c = 0; c < 4; ++c) {
      size_t b = ((size_t)c * NN + r) * 4;
      sab += stq[b + 0]; ssu += stq[b + 1]; ssq += stq[b + 2];
      smx = fmaxf(smx, stq[b + 3]);
    }
    float diag = stPd[r];
    float L1 = fmaxf(sab, 1e-12f);
    float inv = 1.f / L1;
    float stdv = sqrtf(fmaxf((ssq - ssu * ssu * (1.f / 2048.f)) * (1.f / 2047.f), 0.f)) * inv;
    u16* he = hfeB + (size_t)r * 544;
    he[512] = bf1(diag * inv); he[513] = bf1(ssu * inv);
    he[514] = bf1(stdv);       he[515] = bf1(smx * inv);
    s_inv = inv;
  }
  if (t < 14) *(u32*)(hfeB + (size_t)r * 544 + 516 + 2 * t) = 0;
  __syncthreads();
  float inv = s_inv;
  float xv = xmp[(size_t)r * DXF + t] + xmp[(size_t)NN * DXF + (size_t)r * DXF + t] +
             xmp[2 * (size_t)NN * DXF + (size_t)r * DXF + t] +
             xmp[3 * (size_t)NN * DXF + (size_t)r * DXF + t];
  out_xm[(size_t)r * DXF + t] = xv * inv + x[(size_t)r * DXF + t];
}

extern "C" void kernel_launch(void* const* d_in, const int* in_sizes, int n_in,
                              void* d_out, int out_size, void* d_ws, size_t ws_size,
                              hipStream_t stream) {
  (void)in_sizes; (void)n_in; (void)out_size; (void)ws_size;
  const float* h    = (const float*)d_in[0];
  const float* x    = (const float*)d_in[1];
  const float* ln_g = (const float*)d_in[2];
  const float* ln_b = (const float*)d_in[3];
  const float* Wk   = (const float*)d_in[4];
  const float* bk   = (const float*)d_in[5];
  const float* Wq   = (const float*)d_in[6];
  const float* bq   = (const float*)d_in[7];
  const float* Wv   = (const float*)d_in[8];
  const float* bv   = (const float*)d_in[9];
  const float* Wm1  = (const float*)d_in[10];
  const float* bm1  = (const float*)d_in[11];
  const float* Wm2  = (const float*)d_in[12];
  const float* bm2  = (const float*)d_in[13];
  const float* lnf_g = (const float*)d_in[14];
  const float* lnf_b = (const float*)d_in[15];
  const float* Wfc  = (const float*)d_in[16];
  const float* bfc  = (const float*)d_in[17];

  char* wsb = (char*)d_ws;
  size_t off = 0;
  auto alloc = [&](size_t bytes) { char* p = wsb + off; off += (bytes + 255) & ~(size_t)255; return p; };
  u16*   hnB  = (u16*)alloc((size_t)NN * FD * 2);
  u16*   wkB  = (u16*)alloc((size_t)FD * FD * 2);
  u16*   wqB  = (u16*)alloc((size_t)FD * FD * 2);
  u16*   wvB  = (u16*)alloc((size_t)FD * FD * 2);
  u16*   wfcB = (u16*)alloc((size_t)512 * 544 * 2);
  u16*   kP   = (u16*)alloc((size_t)8 * NN * 64 * 2);
  u16*   qP   = (u16*)alloc((size_t)8 * NN * 64 * 2);
  u16*   vPT  = (u16*)alloc((size_t)8 * 64 * NN * 2);
  u16*   xnB  = (u16*)alloc((size_t)NN * DXF * 2);
  u16*   xnTg = (u16*)alloc((size_t)DXF * NN * 2);
  u16*   axg  = (u16*)alloc((size_t)NN * NN * 2);
  u16*   hmp  = (u16*)alloc((size_t)JC * 8 * NN * 64 * 2);
  float* xmp  = (float*)alloc((size_t)4 * NN * DXF * 4);
  float* stq  = (float*)alloc((size_t)4 * NN * 4 * 4);
  float* stPd = (float*)alloc((size_t)NN * 4);
  float* hmf  = (float*)alloc((size_t)NN * FD * 4);
  u16*   hfeB = (u16*)alloc((size_t)NN * 544 * 2);
  float* out_hf = (float*)d_out;
  float* out_xm = out_hf + (size_t)NN * FD;

  preproc_k<<<2 * NN + 1536 + 544, 256, 0, stream>>>(
      h, ln_g, ln_b, hnB, x, xnB, Wk, Wq, Wv, wkB, wqB, wvB, Wfc, wfcB);
  xnt_k<<<NN / 16, 256, 0, stream>>>(xnB, xnTg);

  proj3_k<<<dim3(32, 8, 3), 256, 0, stream>>>(hnB, wkB, wqB, wvB, bk, bq, bv, kP, qP, vPT);

  fused_mfma_k<<<dim3(NN / ITI, JC), 512, 0, stream>>>(kP, qP, vPT, xnB, Wm1, bm1, Wm2, bm2,
                                                       hmp, axg, stPd);

  xm_split_k<<<dim3(32, 4, 4), 256, 0, stream>>>(axg, xnTg, xmp, stq);

  epilogue1_k<<<NN, 256, 0, stream>>>(h, x, hmp, xmp, stq, stPd, lnf_g, lnf_b, hmf, hfeB, out_xm);

  fc_gemm_k<<<dim3(64, 16), 256, 0, stream>>>(hfeB, wfcB, bfc, hmf, out_hf);
}

// Round 13
// 141.265 us; speedup vs baseline: 1.3185x; 1.1303x over previous
//
#include <hip/hip_runtime.h>
#include <math.h>

#define NN 2048
#define FD 512
#define DXF 256
#define JC 8
#define CHKJ (NN/JC)      // 256
#define ITI 32
#define JTW 64
#define NIT (CHKJ/JTW)    // 4
#define KC (NN/4)         // 512 (xm split-K chunk)

typedef unsigned short u16;
typedef unsigned int u32;
typedef __attribute__((ext_vector_type(8))) short s16x8;
typedef __attribute__((ext_vector_type(4))) float f32x4;

__device__ __forceinline__ f32x4 MFMA16(s16x8 a, s16x8 b, f32x4 c) {
  return __builtin_amdgcn_mfma_f32_16x16x32_bf16(a, b, c, 0, 0, 0);
}
__device__ __forceinline__ float blo(u32 u) { return __uint_as_float(u << 16); }
__device__ __forceinline__ float bhi(u32 u) { return __uint_as_float(u & 0xffff0000u); }
__device__ __forceinline__ float b2f(u16 v) { return __uint_as_float((u32)v << 16); }
__device__ __forceinline__ u16 bf1(float f) {
  u32 u = __float_as_uint(f);
  u += 0x7fffu + ((u >> 16) & 1u);
  return (u16)(u >> 16);
}
__device__ __forceinline__ u32 pkbf(float a, float b) {
  u32 ua = __float_as_uint(a), ub = __float_as_uint(b);
  ua += 0x7fffu + ((ua >> 16) & 1u);
  ub += 0x7fffu + ((ub >> 16) & 1u);
  return (ua >> 16) | (ub & 0xffff0000u);
}

// ---------- merged preprocessing: ln rows, xn rows, weight converts ----------
__global__ void preproc_k(
    const float* __restrict__ h, const float* __restrict__ ln_g,
    const float* __restrict__ ln_b, u16* __restrict__ hnB,
    const float* __restrict__ x, u16* __restrict__ xnB,
    const float* __restrict__ Wk, const float* __restrict__ Wq,
    const float* __restrict__ Wv, u16* __restrict__ wkB, u16* __restrict__ wqB,
    u16* __restrict__ wvB, const float* __restrict__ Wfc, u16* __restrict__ wfcB) {
  int bid = blockIdx.x, t = threadIdx.x;
  __shared__ float red[4][2];
  if (bid < NN) {
    int r = bid;
    float2 v = ((const float2*)(h + (size_t)r * FD))[t];
    float2 w = make_float2(v.x + v.y, v.x * v.x + v.y * v.y);
#pragma unroll
    for (int o = 32; o > 0; o >>= 1) { w.x += __shfl_xor(w.x, o); w.y += __shfl_xor(w.y, o); }
    if ((t & 63) == 0) { red[t >> 6][0] = w.x; red[t >> 6][1] = w.y; }
    __syncthreads();
    float S  = (red[0][0] + red[1][0]) + (red[2][0] + red[3][0]);
    float SQ = (red[0][1] + red[1][1]) + (red[2][1] + red[3][1]);
    float mean = S * (1.f / FD);
    float var  = SQ * (1.f / FD) - mean * mean;
    float rs = rsqrtf(var + 1e-5f);
    float2 gg = ((const float2*)ln_g)[t], bb = ((const float2*)ln_b)[t];
    float ox = (v.x - mean) * rs * gg.x + bb.x;
    float oy = (v.y - mean) * rs * gg.y + bb.y;
    *(u32*)(hnB + (size_t)r * FD + 2 * t) = pkbf(ox, oy);
  } else if (bid < 2 * NN) {
    int r = bid - NN;
    float v = x[(size_t)r * DXF + t];
    float s = fabsf(v);
#pragma unroll
    for (int o = 32; o > 0; o >>= 1) s += __shfl_xor(s, o);
    if ((t & 63) == 0) red[t >> 6][0] = s;
    __syncthreads();
    float S = (red[0][0] + red[1][0]) + (red[2][0] + red[3][0]);
    float inv = 1.f / fmaxf(S, 1e-12f);
    xnB[(size_t)r * DXF + t] = bf1(v * inv);
  } else if (bid < 2 * NN + 1536) {
    int idx = bid - 2 * NN;
    int z = idx >> 9;
    int i = ((idx & 511) << 8) + t;
    const float* W = (z == 0) ? Wk : (z == 1) ? Wq : Wv;
    u16* O = (z == 0) ? wkB : (z == 1) ? wqB : wvB;
    float2 v = ((const float2*)W)[i];
    ((u32*)O)[i] = pkbf(v.x, v.y);
  } else {
    int i = (bid - (2 * NN + 1536)) * 256 + t;
    if (i < 512 * 272) {
      int r = i / 272, c2 = (i - r * 272) * 2;
      float a = (c2 < 516) ? Wfc[r * 516 + c2] : 0.f;
      float b = (c2 + 1 < 516) ? Wfc[r * 516 + c2 + 1] : 0.f;
      ((u32*)wfcB)[i] = pkbf(a, b);
    }
  }
}

// ---------- transpose xnB -> xnTg [256][NN]; also emit fragment-packed xnF ----------
// xnF layout: [jt(128)][ks(8)][lane(64)][e(8)] u16; lane = (j&15) | (g<<4), d = ks*32+g*8+e
__global__ void xnt_k(const u16* __restrict__ xnB, u16* __restrict__ xnTg,
                      u16* __restrict__ xnF) {
  __shared__ u16 tile[16][264];
  int t = threadIdx.x;
  int r0 = blockIdx.x * 16;
#pragma unroll
  for (int s = 0; s < 2; ++s) {
    int c = s * 256 + t;
    int db = c & 31, row = c >> 5;
    *(uint4*)&tile[row][db * 8] = *(const uint4*)(xnB + (size_t)(r0 + row) * DXF + db * 8);
  }
  __syncthreads();
#pragma unroll
  for (int s = 0; s < 2; ++s) {
    int c = s * 256 + t;
    int jb = c & 1, d = c >> 1;
    u32 p[4];
#pragma unroll
    for (int e2 = 0; e2 < 4; ++e2) {
      u16 a = tile[jb * 8 + e2 * 2][d], b = tile[jb * 8 + e2 * 2 + 1][d];
      p[e2] = (u32)a | ((u32)b << 16);
    }
    *(uint4*)(xnTg + (size_t)d * NN + r0 + jb * 8) = make_uint4(p[0], p[1], p[2], p[3]);
  }
  // fragment-packed copy
#pragma unroll
  for (int s = 0; s < 2; ++s) {
    int idx = s * 256 + t;            // 0..511
    int ks = idx >> 6, lane = idx & 63;
    int row = lane & 15, db = ks * 32 + (lane >> 4) * 8;
    uint4 v = *(const uint4*)&tile[row][db];
    *(uint4*)(xnF + (((size_t)(r0 >> 4) * 8 + ks) * 64 + lane) * 8) = v;
  }
}

// ---------- batched projection GEMM: z=0 kP planar, z=1 qF packed, z=2 vF packed ----------
__global__ __launch_bounds__(256) void proj3_k(
    const u16* __restrict__ A,
    const u16* __restrict__ W0, const u16* __restrict__ W1, const u16* __restrict__ W2,
    const float* __restrict__ b0, const float* __restrict__ b1, const float* __restrict__ b2,
    u16* __restrict__ kP, u16* __restrict__ qF, u16* __restrict__ vF) {
  int z = blockIdx.z;
  const u16* B = (z == 0) ? W0 : (z == 1) ? W1 : W2;
  const float* bias = (z == 0) ? b0 : (z == 1) ? b1 : b2;
  int t = threadIdx.x, w = t >> 6, lane = t & 63, g = lane >> 4, li = lane & 15;
  int m0 = blockIdx.x * 64 + (w & 1) * 32;
  int n0 = blockIdx.y * 64 + (w >> 1) * 32;
  f32x4 acc[2][2] = {};
  for (int k0 = 0; k0 < FD; k0 += 32) {
    s16x8 a0 = *(const s16x8*)(A + (size_t)(m0 + li) * FD + k0 + g * 8);
    s16x8 a1 = *(const s16x8*)(A + (size_t)(m0 + 16 + li) * FD + k0 + g * 8);
    s16x8 bA = *(const s16x8*)(B + (size_t)(n0 + li) * FD + k0 + g * 8);
    s16x8 bB = *(const s16x8*)(B + (size_t)(n0 + 16 + li) * FD + k0 + g * 8);
    acc[0][0] = MFMA16(a0, bA, acc[0][0]);
    acc[0][1] = MFMA16(a0, bB, acc[0][1]);
    acc[1][0] = MFMA16(a1, bA, acc[1][0]);
    acc[1][1] = MFMA16(a1, bB, acc[1][1]);
  }
#pragma unroll
  for (int ms = 0; ms < 2; ++ms)
#pragma unroll
    for (int ns = 0; ns < 2; ++ns) {
      int ncol = n0 + ns * 16 + li;
      float bv = bias[ncol];
      if (z == 0) {
#pragma unroll
        for (int r = 0; r < 4; ++r) {
          int i = m0 + ms * 16 + g * 4 + r;
          kP[((size_t)(ncol & 7) * NN + i) * 64 + (ncol >> 3)] = bf1(acc[ms][ns][r] + bv);
        }
      } else if (z == 1) {
        // qF: [jt][b][ks][lane][e]; j=i, y=ncol>>3
#pragma unroll
        for (int r = 0; r < 4; ++r) {
          int i = m0 + ms * 16 + g * 4 + r;
          size_t idx = ((size_t)(i >> 4) * 8 + (ncol & 7)) * 1024 +
                       (size_t)(ncol >> 8) * 512 +
                       (size_t)((i & 15) | (((ncol >> 6) & 3) << 4)) * 8 +
                       ((ncol >> 3) & 7);
          qF[idx] = bf1(acc[ms][ns][r] + bv);
        }
      } else {
        // vF: [jb32][hd][zt][lane][e]; j=i (k-dim), z=ncol>>3 (row)
        u16 e4[4];
#pragma unroll
        for (int r = 0; r < 4; ++r) e4[r] = bf1(acc[ms][ns][r] + bv);
        u32 p0 = (u32)e4[0] | ((u32)e4[1] << 16);
        u32 p1 = (u32)e4[2] | ((u32)e4[3] << 16);
        int ibase = m0 + ms * 16 + g * 4;
        int lane_w = ((ncol >> 3) & 15) | (((ibase >> 3) & 3) << 4);
        size_t base = ((((size_t)(m0 >> 5) * 8 + (ncol & 7)) * 4 + (ncol >> 7)) * 64 + lane_w) * 8 +
                      ((g & 1) * 4);
        *(uint2*)(vF + base) = make_uint2(p0, p1);
      }
    }
}

// ---------- fc GEMM (32x32 tiles): elu + residual ----------
__global__ __launch_bounds__(256) void fc_gemm_k(
    const u16* __restrict__ A, const u16* __restrict__ B,
    const float* __restrict__ bias, const float* __restrict__ res,
    float* __restrict__ C) {
  int t = threadIdx.x, w = t >> 6, lane = t & 63, g = lane >> 4, li = lane & 15;
  int m0 = blockIdx.x * 32 + (w & 1) * 16;
  int n0 = blockIdx.y * 32 + (w >> 1) * 16;
  f32x4 acc = {};
  for (int k0 = 0; k0 < 544; k0 += 32) {
    s16x8 a0 = *(const s16x8*)(A + (size_t)(m0 + li) * 544 + k0 + g * 8);
    s16x8 b0 = *(const s16x8*)(B + (size_t)(n0 + li) * 544 + k0 + g * 8);
    acc = MFMA16(a0, b0, acc);
  }
  int ncol = n0 + li;
  float bv = bias[ncol];
#pragma unroll
  for (int r = 0; r < 4; ++r) {
    int i = m0 + g * 4 + r;
    float cv = acc[r] + bv;
    cv = (cv > 0.f) ? cv : (expf(cv) - 1.f);
    cv += res[(size_t)i * FD + ncol];
    C[(size_t)i * FD + ncol] = cv;
  }
}

// ---------- xm GEMM split-K + partial row stats of axg ----------
__global__ __launch_bounds__(256) void xm_split_k(
    const u16* __restrict__ axg, const u16* __restrict__ xnTg,
    float* __restrict__ xmp, float* __restrict__ stq) {
  int t = threadIdx.x, w = t >> 6, lane = t & 63, g = lane >> 4, li = lane & 15;
  int m0 = blockIdx.x * 64 + (w & 1) * 32;
  int n0 = blockIdx.y * 64 + (w >> 1) * 32;
  int z = blockIdx.z;
  const int kb = z * KC;
  f32x4 acc[2][2] = {};
  float sab[2] = {0.f, 0.f}, ssu[2] = {0.f, 0.f}, ssq[2] = {0.f, 0.f};
  float smx[2] = {-1e30f, -1e30f};
  const bool do_stats = (blockIdx.y == 0) && ((w >> 1) == 0);
  for (int k0 = 0; k0 < KC; k0 += 32) {
    s16x8 a0 = *(const s16x8*)(axg + (size_t)(m0 + li) * NN + kb + k0 + g * 8);
    s16x8 a1 = *(const s16x8*)(axg + (size_t)(m0 + 16 + li) * NN + kb + k0 + g * 8);
    s16x8 bA = *(const s16x8*)(xnTg + (size_t)(n0 + li) * NN + kb + k0 + g * 8);
    s16x8 bB = *(const s16x8*)(xnTg + (size_t)(n0 + 16 + li) * NN + kb + k0 + g * 8);
    acc[0][0] = MFMA16(a0, bA, acc[0][0]);
    acc[0][1] = MFMA16(a0, bB, acc[0][1]);
    acc[1][0] = MFMA16(a1, bA, acc[1][0]);
    acc[1][1] = MFMA16(a1, bB, acc[1][1]);
    if (do_stats) {
#pragma unroll
      for (int ms = 0; ms < 2; ++ms) {
        u32 pu[4];
        *(s16x8*)pu = ms ? a1 : a0;
#pragma unroll
        for (int q2 = 0; q2 < 4; ++q2) {
          float x0 = blo(pu[q2]), x1 = bhi(pu[q2]);
          sab[ms] += fabsf(x0) + fabsf(x1);
          ssu[ms] += x0 + x1;
          ssq[ms] += x0 * x0 + x1 * x1;
          smx[ms] = fmaxf(smx[ms], fmaxf(x0, x1));
        }
      }
    }
  }
  if (do_stats) {
#pragma unroll
    for (int off = 16; off < 64; off <<= 1) {
#pragma unroll
      for (int ms = 0; ms < 2; ++ms) {
        sab[ms] += __shfl_xor(sab[ms], off);
        ssu[ms] += __shfl_xor(ssu[ms], off);
        ssq[ms] += __shfl_xor(ssq[ms], off);
        smx[ms] = fmaxf(smx[ms], __shfl_xor(smx[ms], off));
      }
    }
    if (g == 0) {
#pragma unroll
      for (int ms = 0; ms < 2; ++ms) {
        size_t base = ((size_t)z * NN + m0 + ms * 16 + li) * 4;
        stq[base + 0] = sab[ms]; stq[base + 1] = ssu[ms];
        stq[base + 2] = ssq[ms]; stq[base + 3] = smx[ms];
      }
    }
  }
#pragma unroll
  for (int ms = 0; ms < 2; ++ms)
#pragma unroll
    for (int ns = 0; ns < 2; ++ns) {
      int ncol = n0 + ns * 16 + li;
#pragma unroll
      for (int r = 0; r < 4; ++r) {
        int i = m0 + ms * 16 + g * 4 + r;
        xmp[(size_t)z * NN * DXF + (size_t)i * DXF + ncol] = acc[ms][ns][r];
      }
    }
}

// ---------- fused pairwise kernel (R12 + fragment-packed B-side loads) ----------
// grid (64, 8); 512 threads = 8 waves. i-tile 32, j-iter 64, 4 iters.
// LDS 80 KB: kI (32K) | xnI (16K) | P (32K), all XOR-swizzled as in R6.
// B-side operands (q, xn-j, V) read from fragment-packed buffers: one wave load = 1KB contiguous.
__global__ __launch_bounds__(512, 2) void fused_mfma_k(
    const u16* __restrict__ kP, const u16* __restrict__ qF,
    const u16* __restrict__ vF, const u16* __restrict__ xnB,
    const u16* __restrict__ xnF,
    const float* __restrict__ Wm1, const float* __restrict__ bm1,
    const float* __restrict__ Wm2, const float* __restrict__ bm2,
    u16* __restrict__ hmPart, u16* __restrict__ axg, float* __restrict__ stPd) {
  __shared__ __align__(16) unsigned char L[81920];
  const int O_KI = 0, O_XNI = 32768, O_P = 49152;
  const int t = threadIdx.x, w = t >> 6, lane = t & 63;
  const int g = lane >> 4, li = lane & 15;
  const int i0 = blockIdx.x * ITI, chunk = blockIdx.y;
  const int si = w & 1;                 // i-subtile (scores & PV)
  const int jw = w >> 1;
  const int jL = jw * 16 + li;          // score j within 64
  const int iRow = si * 16 + li;        // A-frag row
  const int prow = si * 16 + li;

  float W1[8][9], B1v[8], w2v[8];
#pragma unroll
  for (int o = 0; o < 8; ++o) {
    B1v[o] = bm1[o];
    w2v[o] = Wm2[o];
#pragma unroll
    for (int b3 = 0; b3 < 9; ++b3) W1[o][b3] = Wm1[o * 9 + b3];
  }
  const float b2v = bm2[0];

  // stage kI + xnI once per block (XOR-swizzled)
#pragma unroll
  for (int s = 0; s < 4; ++s) {
    int c = s * 512 + t;
    int yb = c & 7, il = (c >> 3) & 31, b = c >> 8;
    uint4 v = *(const uint4*)(kP + ((size_t)b * NN + i0 + il) * 64 + yb * 8);
    *(uint4*)(L + O_KI + b * 4096 + il * 128 + ((yb ^ (il & 7)) << 4)) = v;
  }
#pragma unroll
  for (int s = 0; s < 2; ++s) {
    int c = s * 512 + t;
    int db = c & 31, il = c >> 5;
    uint4 v = *(const uint4*)(xnB + (size_t)(i0 + il) * DXF + db * 8);
    *(uint4*)(L + O_XNI + il * 512 + ((db ^ (il & 7)) << 4)) = v;
  }
  __syncthreads();

  f32x4 hmA[2][4];
#pragma unroll
  for (int a = 0; a < 2; ++a)
#pragma unroll
    for (int c = 0; c < 4; ++c) hmA[a][c] = (f32x4)(0.f);

  for (int it = 0; it < NIT; ++it) {
    const int j0 = chunk * CHKJ + it * JTW;
    const int jt = (j0 >> 4) + jw;      // this wave's 16-j tile index
    const int jb32 = j0 >> 5;
    // ---- phase 1: scores (A from LDS, B from packed global) ----
    f32x4 accS[9];
#pragma unroll
    for (int a = 0; a < 9; ++a) accS[a] = (f32x4)(0.f);
#pragma unroll
    for (int b = 0; b < 8; ++b)
#pragma unroll
      for (int ks = 0; ks < 2; ++ks) {
        int blk = ks * 4 + g;
        s16x8 af = *(const s16x8*)(L + O_KI + b * 4096 + iRow * 128 +
                                   ((blk ^ (iRow & 7)) << 4));
        s16x8 bf = *(const s16x8*)(qF + (((size_t)jt * 8 + b) * 2 + ks) * 512 +
                                   (size_t)lane * 8);
        accS[b] = MFMA16(af, bf, accS[b]);
      }
#pragma unroll
    for (int ks = 0; ks < 8; ++ks) {
      int blk = ks * 4 + g;
      s16x8 af = *(const s16x8*)(L + O_XNI + iRow * 512 + ((blk ^ (iRow & 7)) << 4));
      s16x8 bf = *(const s16x8*)(xnF + ((size_t)jt * 8 + ks) * 512 + (size_t)lane * 8);
      accS[8] = MFMA16(af, bf, accS[8]);
    }
    // ---- V prefetch (hh=0 half): issue before softmax ----
    s16x8 vf0[2][4];
#pragma unroll
    for (int kb = 0; kb < 2; ++kb)
#pragma unroll
      for (int zt = 0; zt < 4; ++zt)
        vf0[kb][zt] = *(const s16x8*)(vF + ((((size_t)(jb32 + kb) * 8 + jw * 2 + 0) * 4 + zt) * 512) +
                                      (size_t)lane * 8);
    __syncthreads();  // previous PV done reading P
    // ---- mixing + softmax + P/axn ----
#pragma unroll
    for (int r = 0; r < 4; ++r) {
      float sb[8];
#pragma unroll
      for (int b = 0; b < 8; ++b) sb[b] = accS[b][r];
      float ax = accS[8][r];
      float m[8];
#pragma unroll
      for (int o = 0; o < 8; ++o) {
        float a = B1v[o] + W1[o][0] * ax;
#pragma unroll
        for (int b = 0; b < 8; ++b) a += W1[o][1 + b] * sb[b];
        m[o] = a;
      }
      float axn = b2v + ax;
#pragma unroll
      for (int o = 0; o < 8; ++o) axn += w2v[o] * m[o];
      const int iL2 = si * 16 + g * 4 + r;
      const int iG = i0 + iL2, jG = j0 + jL;
      axg[(size_t)iG * NN + jG] = bf1(axn);
      if (iG == jG) stPd[iG] = axn;
      float mx = m[0];
#pragma unroll
      for (int o = 1; o < 8; ++o) mx = fmaxf(mx, m[o]);
      float es[8], esum = 0.f;
#pragma unroll
      for (int o = 0; o < 8; ++o) { es[o] = __expf(m[o] - mx); esum += es[o]; }
      float inv = 1.f / esum;
      const int base = iL2 * 128 + (((jL >> 3) ^ (iL2 & 7)) << 4) + (jL & 7) * 2;
#pragma unroll
      for (int b = 0; b < 8; ++b)
        *(u16*)(L + O_P + b * 4096 + base) = bf1(es[b] * inv);
    }
    // ---- V prefetch (hh=1 half) ----
    s16x8 vf1[2][4];
#pragma unroll
    for (int kb = 0; kb < 2; ++kb)
#pragma unroll
      for (int zt = 0; zt < 4; ++zt)
        vf1[kb][zt] = *(const s16x8*)(vF + ((((size_t)(jb32 + kb) * 8 + jw * 2 + 1) * 4 + zt) * 512) +
                                      (size_t)lane * 8);
    __syncthreads();  // P visible
    // ---- phase 2: PV (A=P from LDS, B=prefetched registers) ----
#pragma unroll
    for (int hh = 0; hh < 2; ++hh) {
      const int hd = jw * 2 + hh;
#pragma unroll
      for (int kb = 0; kb < 2; ++kb) {
        s16x8 pa = *(const s16x8*)(L + O_P + hd * 4096 + prow * 128 +
                                   (((kb * 4 + g) ^ (prow & 7)) << 4));
#pragma unroll
        for (int zt = 0; zt < 4; ++zt) {
          s16x8 vf = hh ? vf1[kb][zt] : vf0[kb][zt];
          hmA[hh][zt] = MFMA16(pa, vf, hmA[hh][zt]);
        }
      }
    }
  }
  // ---- write hm partials (bf16) ----
#pragma unroll
  for (int hh = 0; hh < 2; ++hh) {
    const int hd = jw * 2 + hh;
#pragma unroll
    for (int zt = 0; zt < 4; ++zt)
#pragma unroll
      for (int r = 0; r < 4; ++r) {
        int i = i0 + si * 16 + g * 4 + r;
        int z = zt * 16 + li;
        hmPart[((size_t)(chunk * 8 + hd) * NN + i) * 64 + z] = bf1(hmA[hh][zt][r]);
      }
  }
}

// ---------- epilogue ----------
__global__ void epilogue1_k(
    const float* __restrict__ h, const float* __restrict__ x,
    const u16* __restrict__ hmp, const float* __restrict__ xmp,
    const float* __restrict__ stq, const float* __restrict__ stPd,
    const float* __restrict__ lnf_g, const float* __restrict__ lnf_b,
    float* __restrict__ hmf, u16* __restrict__ hfeB, float* __restrict__ out_xm) {
  int r = blockIdx.x, t = threadIdx.x;
  int c0 = 2 * t, c1 = c0 + 1;
  float2 acc = ((const float2*)(h + (size_t)r * FD))[t];
#pragma unroll
  for (int ch = 0; ch < JC; ++ch) {
    acc.x += b2f(hmp[((size_t)(ch * 8 + (c0 & 7)) * NN + r) * 64 + (c0 >> 3)]);
    acc.y += b2f(hmp[((size_t)(ch * 8 + (c1 & 7)) * NN + r) * 64 + (c1 >> 3)]);
  }
  ((float2*)(hmf + (size_t)r * FD))[t] = acc;
  float2 w = make_float2(acc.x + acc.y, acc.x * acc.x + acc.y * acc.y);
#pragma unroll
  for (int o = 32; o > 0; o >>= 1) { w.x += __shfl_xor(w.x, o); w.y += __shfl_xor(w.y, o); }
  __shared__ float red[4][2];
  __shared__ float s_inv;
  if ((t & 63) == 0) { red[t >> 6][0] = w.x; red[t >> 6][1] = w.y; }
  __syncthreads();
  float S  = (red[0][0] + red[1][0]) + (red[2][0] + red[3][0]);
  float SQ = (red[0][1] + red[1][1]) + (red[2][1] + red[3][1]);
  float mean = S * (1.f / FD);
  float var  = SQ * (1.f / FD) - mean * mean;
  float rs = rsqrtf(var + 1e-5f);
  float2 g2 = ((const float2*)lnf_g)[t], b2 = ((const float2*)lnf_b)[t];
  float ox = (acc.x - mean) * rs * g2.x + b2.x;
  float oy = (acc.y - mean) * rs * g2.y + b2.y;
  *(u32*)(hfeB + (size_t)r * 544 + c0) = pkbf(ox, oy);
  if (t == 0) {
    float sab = 0.f, ssu = 0.f, ssq = 0.f, smx = -1e30f;
#pragma unroll
    for (int c = 0; c < 4; ++c) {
      size_t b = ((size_t)c * NN + r) * 4;
      sab += stq[b + 0]; ssu += stq[b + 1]; ssq += stq[b + 2];
      smx = fmaxf(smx, stq[b + 3]);
    }
    float diag = stPd[r];
    float L1 = fmaxf(sab, 1e-12f);
    float inv = 1.f / L1;
    float stdv = sqrtf(fmaxf((ssq - ssu * ssu * (1.f / 2048.f)) * (1.f / 2047.f), 0.f)) * inv;
    u16* he = hfeB + (size_t)r * 544;
    he[512] = bf1(diag * inv); he[513] = bf1(ssu * inv);
    he[514] = bf1(stdv);       he[515] = bf1(smx * inv);
    s_inv = inv;
  }
  if (t < 14) *(u32*)(hfeB + (size_t)r * 544 + 516 + 2 * t) = 0;
  __syncthreads();
  float inv = s_inv;
  float xv = xmp[(size_t)r * DXF + t] + xmp[(size_t)NN * DXF + (size_t)r * DXF + t] +
             xmp[2 * (size_t)NN * DXF + (size_t)r * DXF + t] +
             xmp[3 * (size_t)NN * DXF + (size_t)r * DXF + t];
  out_xm[(size_t)r * DXF + t] = xv * inv + x[(size_t)r * DXF + t];
}

extern "C" void kernel_launch(void* const* d_in, const int* in_sizes, int n_in,
                              void* d_out, int out_size, void* d_ws, size_t ws_size,
                              hipStream_t stream) {
  (void)in_sizes; (void)n_in; (void)out_size; (void)ws_size;
  const float* h    = (const float*)d_in[0];
  const float* x    = (const float*)d_in[1];
  const float* ln_g = (const float*)d_in[2];
  const float* ln_b = (const float*)d_in[3];
  const float* Wk   = (const float*)d_in[4];
  const float* bk   = (const float*)d_in[5];
  const float* Wq   = (const float*)d_in[6];
  const float* bq   = (const float*)d_in[7];
  const float* Wv   = (const float*)d_in[8];
  const float* bv   = (const float*)d_in[9];
  const float* Wm1  = (const float*)d_in[10];
  const float* bm1  = (const float*)d_in[11];
  const float* Wm2  = (const float*)d_in[12];
  const float* bm2  = (const float*)d_in[13];
  const float* lnf_g = (const float*)d_in[14];
  const float* lnf_b = (const float*)d_in[15];
  const float* Wfc  = (const float*)d_in[16];
  const float* bfc  = (const float*)d_in[17];

  char* wsb = (char*)d_ws;
  size_t off = 0;
  auto alloc = [&](size_t bytes) { char* p = wsb + off; off += (bytes + 255) & ~(size_t)255; return p; };
  u16*   hnB  = (u16*)alloc((size_t)NN * FD * 2);
  u16*   wkB  = (u16*)alloc((size_t)FD * FD * 2);
  u16*   wqB  = (u16*)alloc((size_t)FD * FD * 2);
  u16*   wvB  = (u16*)alloc((size_t)FD * FD * 2);
  u16*   wfcB = (u16*)alloc((size_t)512 * 544 * 2);
  u16*   kP   = (u16*)alloc((size_t)8 * NN * 64 * 2);
  u16*   qF   = (u16*)alloc((size_t)8 * NN * 64 * 2);
  u16*   vF   = (u16*)alloc((size_t)8 * 64 * NN * 2);
  u16*   xnB  = (u16*)alloc((size_t)NN * DXF * 2);
  u16*   xnTg = (u16*)alloc((size_t)DXF * NN * 2);
  u16*   xnF  = (u16*)alloc((size_t)NN * DXF * 2);
  u16*   axg  = (u16*)alloc((size_t)NN * NN * 2);
  u16*   hmp  = (u16*)alloc((size_t)JC * 8 * NN * 64 * 2);
  float* xmp  = (float*)alloc((size_t)4 * NN * DXF * 4);
  float* stq  = (float*)alloc((size_t)4 * NN * 4 * 4);
  float* stPd = (float*)alloc((size_t)NN * 4);
  float* hmf  = (float*)alloc((size_t)NN * FD * 4);
  u16*   hfeB = (u16*)alloc((size_t)NN * 544 * 2);
  float* out_hf = (float*)d_out;
  float* out_xm = out_hf + (size_t)NN * FD;

  preproc_k<<<2 * NN + 1536 + 544, 256, 0, stream>>>(
      h, ln_g, ln_b, hnB, x, xnB, Wk, Wq, Wv, wkB, wqB, wvB, Wfc, wfcB);
  xnt_k<<<NN / 16, 256, 0, stream>>>(xnB, xnTg, xnF);

  proj3_k<<<dim3(32, 8, 3), 256, 0, stream>>>(hnB, wkB, wqB, wvB, bk, bq, bv, kP, qF, vF);

  fused_mfma_k<<<dim3(NN / ITI, JC), 512, 0, stream>>>(kP, qF, vF, xnB, xnF,
                                                       Wm1, bm1, Wm2, bm2,
                                                       hmp, axg, stPd);

  xm_split_k<<<dim3(32, 4, 4), 256, 0, stream>>>(axg, xnTg, xmp, stq);

  epilogue1_k<<<NN, 256, 0, stream>>>(h, x, hmp, xmp, stq, stPd, lnf_g, lnf_b, hmf, hfeB, out_xm);

  fc_gemm_k<<<dim3(64, 16), 256, 0, stream>>>(hfeB, wfcB, bfc, hmf, out_hf);
}